// Round 2
// baseline (306.856 us; speedup 1.0000x reference)
//
#include <hip/hip_runtime.h>
#include <hip/hip_bf16.h>

#define BATCH 8
#define NPTS  131072
#define DIM   32
#define NLAB  33
#define G1X   256             // pass1 blocks per batch -> 2048 total = 8/CU (occupancy fix)
#define P1PTS 512             // points per pass1 block (128 per wave, 4 steps)
#define BPB2  512             // pass2 blocks per batch

// ws float layout
#define OFF_CNT   0                    // BATCH*NLAB = 264
#define OFF_SUM   264                  // BATCH*NLAB*DIM = 8448
#define OFF_PULL  (264 + 8448)         // 8
#define WS_FLOATS (OFF_PULL + 8)

typedef short  bf16x8 __attribute__((ext_vector_type(8)));
typedef float  f32x4  __attribute__((ext_vector_type(4)));

static __device__ __forceinline__ short f2bf(float f) {
  __hip_bfloat16 h = __float2bfloat16(f);
  return *reinterpret_cast<short*>(&h);
}

// Pass 1: sums[l][d] = onehot(labels)^T @ E  via MFMA one-hot GEMM.
// R4 post-mortem: sort+walk was a divergent dependent-LDS chain behind 5
// barriers/chunk -> latency-bound at 32% occ. This version: wave-private
// staging (no barriers in hot loop), one-hot A built from shuffled labels,
// 6 mfma_f32_16x16x32_bf16 per 32 points, counts from the compare bits.
// R6: grid 1024->2048 blocks (P1PTS 1024->512): was grid-limited to 16
// waves/CU (50%); VGPR/LDS allow ~24. More waves to hide the stage->read
// ->mfma latency chain.
__global__ __launch_bounds__(256) void pass1_kernel(
    const float* __restrict__ emb, const int* __restrict__ lab,
    float* __restrict__ gsum, float* __restrict__ gcnt) {
  const int b    = blockIdx.y;
  const int tid  = threadIdx.x;
  const int w    = tid >> 6;
  const int lane = tid & 63;

  constexpr int STEPS = P1PTS / 128;   // 4: each wave = STEPS*32 points

  // wave-private transposed tile: st[d*33 + p], d=dim 0..31, p=point 0..31
  // write bank = (4*(i&7)... ) -> 2-way max (free); B-read bank = (n+8g+j)%32
  // -> 2-way max (free).
  __shared__ float s_stage[4][32 * 33];   // 16.9 KB
  __shared__ int   s_cnt4[4][NLAB];
  float* st = s_stage[w];

  const size_t base = (size_t)b * NPTS + (size_t)blockIdx.x * P1PTS
                    + (size_t)w * (P1PTS / 4);

  const int m0 = lane & 15;      // A row (label within tile), B col (dim)
  const int g  = lane >> 4;      // k-group
  f32x4 acc[3][2];
#pragma unroll
  for (int t = 0; t < 3; ++t)
#pragma unroll
    for (int u = 0; u < 2; ++u) acc[t][u] = (f32x4){0.f, 0.f, 0.f, 0.f};
  int cnt0 = 0, cnt1 = 0, cnt2 = 0;

  // prologue: prefetch step 0
  float4 ld[4];
  int labv;
  {
    const float4* src = (const float4*)(emb + base * DIM);
#pragma unroll
    for (int r = 0; r < 4; ++r) ld[r] = src[lane + 64 * r];
    labv = lab[base + (lane & 31)];
  }

  for (int step = 0; step < STEPS; ++step) {
    // stage current step into wave-private LDS, transposed [dim][point]
#pragma unroll
    for (int r = 0; r < 4; ++r) {
      const int i = lane + 64 * r;
      const int p = i >> 3, d0 = (i & 7) * 4;
      st[(d0 + 0) * 33 + p] = ld[r].x;
      st[(d0 + 1) * 33 + p] = ld[r].y;
      st[(d0 + 2) * 33 + p] = ld[r].z;
      st[(d0 + 3) * 33 + p] = ld[r].w;
    }
    const int labv_c = labv;

    // prefetch next step (overlaps with compute below)
    if (step < STEPS - 1) {
      const float4* src = (const float4*)(emb + (base + (step + 1) * 32) * DIM);
#pragma unroll
      for (int r = 0; r < 4; ++r) ld[r] = src[lane + 64 * r];
      labv = lab[base + (step + 1) * 32 + (lane & 31)];
    }

    // A fragments: one-hot, 3 label tiles; counts ride along as int adds
    bf16x8 a0, a1, a2;
#pragma unroll
    for (int j = 0; j < 8; ++j) {
      const int lj = __shfl(labv_c, g * 8 + j);
      const int h0 = (lj == m0), h1 = (lj == m0 + 16), h2 = (lj == m0 + 32);
      a0[j] = h0 ? (short)0x3F80 : (short)0;
      a1[j] = h1 ? (short)0x3F80 : (short)0;
      a2[j] = h2 ? (short)0x3F80 : (short)0;
      cnt0 += h0; cnt1 += h1; cnt2 += h2;
    }

    // B fragments: E[k][n] from LDS, n = m0 (+16), k = g*8+j
    bf16x8 b0, b1;
#pragma unroll
    for (int j = 0; j < 8; ++j) {
      b0[j] = f2bf(st[m0 * 33 + g * 8 + j]);
      b1[j] = f2bf(st[(m0 + 16) * 33 + g * 8 + j]);
    }

    acc[0][0] = __builtin_amdgcn_mfma_f32_16x16x32_bf16(a0, b0, acc[0][0], 0, 0, 0);
    acc[0][1] = __builtin_amdgcn_mfma_f32_16x16x32_bf16(a0, b1, acc[0][1], 0, 0, 0);
    acc[1][0] = __builtin_amdgcn_mfma_f32_16x16x32_bf16(a1, b0, acc[1][0], 0, 0, 0);
    acc[1][1] = __builtin_amdgcn_mfma_f32_16x16x32_bf16(a1, b1, acc[1][1], 0, 0, 0);
    acc[2][0] = __builtin_amdgcn_mfma_f32_16x16x32_bf16(a2, b0, acc[2][0], 0, 0, 0);
    acc[2][1] = __builtin_amdgcn_mfma_f32_16x16x32_bf16(a2, b1, acc[2][1], 0, 0, 0);
  }

  // counts: reduce across the 4 k-groups (lanes l, l+16, l+32, l+48)
  cnt0 += __shfl_xor(cnt0, 16); cnt0 += __shfl_xor(cnt0, 32);
  cnt1 += __shfl_xor(cnt1, 16); cnt1 += __shfl_xor(cnt1, 32);
  cnt2 += __shfl_xor(cnt2, 16); cnt2 += __shfl_xor(cnt2, 32);
  if (lane < 16)            s_cnt4[w][m0]      = cnt0;
  else if (lane < 32)       s_cnt4[w][m0 + 16] = cnt1;
  if (lane == 32)           s_cnt4[w][32]      = cnt2;

  // per-wave epilogue: dump accumulators into the (now free) staging buffer
  // as [label][dim] (33*32 = 1056 floats, exactly the buffer size).
  // D layout: row(label-in-tile) = g*4 + r, col(dim) = m0 (+16u).
#pragma unroll
  for (int t = 0; t < 2; ++t)
#pragma unroll
    for (int u = 0; u < 2; ++u)
#pragma unroll
      for (int r = 0; r < 4; ++r)
        st[(t * 16 + g * 4 + r) * DIM + m0 + 16 * u] = acc[t][u][r];
  if (lane < 16) {
    st[32 * DIM + m0]      = acc[2][0][0];
    st[32 * DIM + m0 + 16] = acc[2][1][0];
  }
  __syncthreads();

  // cross-wave reduce + global atomics (1056 + 33 per block)
  for (int i = tid; i < NLAB * DIM; i += 256) {
    const float v = s_stage[0][i] + s_stage[1][i] + s_stage[2][i] + s_stage[3][i];
    atomicAdd(&gsum[(size_t)b * (NLAB * DIM) + i], v);
  }
  if (tid < NLAB) {
    const int c = s_cnt4[0][tid] + s_cnt4[1][tid] + s_cnt4[2][tid] + s_cnt4[3][tid];
    atomicAdd(&gcnt[b * NLAB + tid], (float)c);
  }
}

// Pass 2: per-point hinge, weight-folded into registers; one atomic per block.
// R6 post-mortem of R5: VGPR_Count=20 proved the compiler serialized the
// 8-iteration load->compute chain (8 float4 loads in flight need 32 VGPRs
// alone) -> latency-bound: VALUBusy 15%, hbm 10.8%, MfmaUtil 0. This
// version hand-batches the MLP: all 8 label loads, then all 8 emb float4
// loads into a register array, then all 8 LDS mean reads, then compute,
// then 8 INDEPENDENT interleaved shuffle-reduce chains. ~70-90 VGPR,
// still >=5 waves/SIMD at 256 threads.
__global__ __launch_bounds__(256) void pass2_kernel(
    const float* __restrict__ emb, const int* __restrict__ lab,
    const float* __restrict__ gsum, const float* __restrict__ gcnt,
    float* __restrict__ pullb) {
  const int b   = blockIdx.y;
  const int tid = threadIdx.x;
  __shared__ __align__(16) float s_mean[NLAB * 36];
  __shared__ float s_w[NLAB];
  __shared__ float s_red[4];

  for (int i = tid; i < NLAB * DIM; i += 256) {
    const int l = i >> 5, d = i & 31;
    const float c = gcnt[b * NLAB + l];
    s_mean[l * 36 + d] = gsum[b * (NLAB * DIM) + i] / fmaxf(c, 1.0f);
  }
  if (tid < 64) {
    const float c = (tid < NLAB) ? gcnt[b * NLAB + tid] : 0.f;
    const int pres = (tid >= 1 && tid < NLAB && c > 0.f) ? 1 : 0;
    const unsigned long long bal = __ballot(pres);
    const float n_inst = (float)__popcll(bal);
    if (tid < NLAB)
      s_w[tid] = pres ? 1.f / (fmaxf(c, 1.f) * (n_inst + 1e-6f)) : 0.f;
  }
  __syncthreads();

  const int sub   = tid >> 3;
  const int lane8 = tid & 7;
  const int d0    = lane8 << 2;
  const size_t base = (size_t)b * NPTS;
  const int p0 = blockIdx.x * 32 + sub;
  constexpr int NIT     = NPTS / (BPB2 * 32);   // 8
  constexpr int PSTRIDE = BPB2 * 32;            // 16384

  // 1) all labels in flight
  int labs[NIT];
#pragma unroll
  for (int it = 0; it < NIT; ++it)
    labs[it] = lab[base + p0 + it * PSTRIDE];

  // 2) all embedding float4s in flight (8-deep MLP)
  float4 e[NIT];
#pragma unroll
  for (int it = 0; it < NIT; ++it)
    e[it] = *(const float4*)(emb + (base + p0 + (size_t)it * PSTRIDE) * DIM + d0);

  // 3) LDS mean reads + per-lane partial sum of squares
  float s[NIT];
#pragma unroll
  for (int it = 0; it < NIT; ++it) {
    const float4 m = *(const float4*)(s_mean + labs[it] * 36 + d0);
    const float dx = e[it].x - m.x, dy = e[it].y - m.y;
    const float dz = e[it].z - m.z, dw = e[it].w - m.w;
    s[it] = dx * dx + dy * dy + dz * dz + dw * dw;
  }

  // 4) 8 independent 3-deep shuffle chains (interleaved by the scheduler)
#pragma unroll
  for (int it = 0; it < NIT; ++it) {
    s[it] += __shfl_xor(s[it], 1);
    s[it] += __shfl_xor(s[it], 2);
    s[it] += __shfl_xor(s[it], 4);
  }

  float wacc = 0.f;
  if (lane8 == 0) {
#pragma unroll
    for (int it = 0; it < NIT; ++it) {
      const float dist = sqrtf(s[it] + 1e-24f);
      wacc += s_w[labs[it]] * fmaxf(dist - 0.1f, 0.f);
    }
  }
#pragma unroll
  for (int m = 1; m < 64; m <<= 1) wacc += __shfl_xor(wacc, m);
  if ((tid & 63) == 0) s_red[tid >> 6] = wacc;
  __syncthreads();
  if (tid == 0)
    atomicAdd(&pullb[b], s_red[0] + s_red[1] + s_red[2] + s_red[3]);
}

// Per-batch push + final combine. One wave per batch, single block.
__global__ __launch_bounds__(512) void finish_kernel(
    const float* __restrict__ gsum, const float* __restrict__ gcnt,
    const float* __restrict__ pullb, float* __restrict__ out) {
  const int tid = threadIdx.x;
  const int b   = tid >> 6;
  const int t   = tid & 63;
  __shared__ __align__(16) float s_mn[BATCH * 32 * DIM];
  __shared__ float s_ps[BATCH];
  float* mn = s_mn + b * 32 * DIM;

  int pres = 0;
  if (t < 32) {
    const int l = t + 1;
    const float cnt = gcnt[b * NLAB + l];
    pres = (cnt > 0.f) ? 1 : 0;
    const float inv = 1.f / fmaxf(cnt, 1.f);
    float v[DIM];
    float n2 = 0.f;
    for (int d = 0; d < DIM; d++) {
      v[d] = gsum[b * (NLAB * DIM) + l * DIM + d] * inv;
      n2  += v[d] * v[d];
    }
    const float scale = 1.f / fmaxf(sqrtf(n2), 1e-12f);
    for (int d = 0; d < DIM; d++) mn[t * DIM + d] = v[d] * scale;
  }
  const unsigned long long bal = __ballot(pres);
  const unsigned int pmask32 = (unsigned int)(bal & 0xFFFFFFFFull);
  const int n_inst = __popc(pmask32);

  __syncthreads();

  float hp_sum = 0.f, pm_sum = 0.f;
  for (int idx = t; idx < 1024; idx += 64) {
    const int i = idx >> 5, j = idx & 31;
    if (j > i && ((pmask32 >> i) & 1u) && ((pmask32 >> j) & 1u)) {
      const float4* a = (const float4*)(mn + i * DIM);
      const float4* c = (const float4*)(mn + j * DIM);
      float sq = 0.f;
      for (int q = 0; q < 8; q++) {
        const float4 av = a[q], cv = c[q];
        const float dx = av.x - cv.x, dy = av.y - cv.y;
        const float dz = av.z - cv.z, dw = av.w - cv.w;
        sq += dx * dx + dy * dy + dz * dz + dw * dw;
      }
      const float dmat = sqrtf(sq + 1e-24f);
      hp_sum += fmaxf(1.0f - dmat, 0.f);   // 2*DELTA_D = 1.0
      pm_sum += 1.f;
    }
  }
  for (int m = 1; m < 64; m <<= 1) {
    hp_sum += __shfl_xor(hp_sum, m);
    pm_sum += __shfl_xor(pm_sum, m);
  }
  const float push = (n_inst > 1) ? hp_sum / (pm_sum + 1e-6f) : 0.f;
  if (t == 0) s_ps[b] = push;
  __syncthreads();

  if (tid < 64) {
    float pl = (t < BATCH) ? pullb[t] : 0.f;
    float ps = (t < BATCH) ? s_ps[t] : 0.f;
#pragma unroll
    for (int m = 1; m < 64; m <<= 1) {
      pl += __shfl_xor(pl, m);
      ps += __shfl_xor(ps, m);
    }
    if (t == 0) {
      const float pull_m = pl / (float)BATCH;
      const float push_m = ps / (float)BATCH;
      out[0] = pull_m + push_m;
      out[1] = pull_m;
      out[2] = push_m;
    }
  }
}

extern "C" void kernel_launch(void* const* d_in, const int* in_sizes, int n_in,
                              void* d_out, int out_size, void* d_ws, size_t ws_size,
                              hipStream_t stream) {
  const float* emb = (const float*)d_in[0];
  const int*   lab = (const int*)d_in[1];
  float* out = (float*)d_out;
  float* ws  = (float*)d_ws;

  float* gcnt  = ws + OFF_CNT;
  float* gsum  = ws + OFF_SUM;
  float* pullb = ws + OFF_PULL;

  hipMemsetAsync(d_ws, 0, WS_FLOATS * sizeof(float), stream);

  dim3 grid1(G1X, BATCH);
  dim3 grid2(BPB2, BATCH);
  pass1_kernel<<<grid1, 256, 0, stream>>>(emb, lab, gsum, gcnt);
  pass2_kernel<<<grid2, 256, 0, stream>>>(emb, lab, gsum, gcnt, pullb);
  finish_kernel<<<1, 512, 0, stream>>>(gsum, gcnt, pullb, out);
}

// Round 3
// 304.608 us; speedup vs baseline: 1.0074x; 1.0074x over previous
//
#include <hip/hip_runtime.h>
#include <hip/hip_bf16.h>

#define BATCH 8
#define NPTS  131072
#define DIM   32
#define NLAB  33
#define G1X   256             // pass1 blocks per batch -> 2048 total = 8/CU
#define P1PTS 512             // points per pass1 block (128 per wave, 4 steps)
#define BPB2  512             // pass2 blocks per batch

// ws float layout
#define OFF_CNT   0                    // BATCH*NLAB = 264
#define OFF_SUM   264                  // BATCH*NLAB*DIM = 8448
#define OFF_PULL  (264 + 8448)         // 8
#define WS_FLOATS (OFF_PULL + 8)

typedef short  bf16x8 __attribute__((ext_vector_type(8)));
typedef float  f32x4  __attribute__((ext_vector_type(4)));

static __device__ __forceinline__ short f2bf(float f) {
  __hip_bfloat16 h = __float2bfloat16(f);
  return *reinterpret_cast<short*>(&h);
}

// Pass 1: sums[l][d] = onehot(labels)^T @ E  via MFMA one-hot GEMM.
// Wave-private staging (no barriers in hot loop), one-hot A built from
// shuffled labels, 6 mfma_f32_16x16x32_bf16 per 32 points, counts from the
// compare bits. R6: 2048 blocks (P1PTS 512) for occupancy.
__global__ __launch_bounds__(256) void pass1_kernel(
    const float* __restrict__ emb, const int* __restrict__ lab,
    float* __restrict__ gsum, float* __restrict__ gcnt) {
  const int b    = blockIdx.y;
  const int tid  = threadIdx.x;
  const int w    = tid >> 6;
  const int lane = tid & 63;

  constexpr int STEPS = P1PTS / 128;   // 4: each wave = STEPS*32 points

  // wave-private transposed tile: st[d*33 + p], d=dim 0..31, p=point 0..31
  __shared__ float s_stage[4][32 * 33];   // 16.9 KB
  __shared__ int   s_cnt4[4][NLAB];
  float* st = s_stage[w];

  const size_t base = (size_t)b * NPTS + (size_t)blockIdx.x * P1PTS
                    + (size_t)w * (P1PTS / 4);

  const int m0 = lane & 15;      // A row (label within tile), B col (dim)
  const int g  = lane >> 4;      // k-group
  f32x4 acc[3][2];
#pragma unroll
  for (int t = 0; t < 3; ++t)
#pragma unroll
    for (int u = 0; u < 2; ++u) acc[t][u] = (f32x4){0.f, 0.f, 0.f, 0.f};
  int cnt0 = 0, cnt1 = 0, cnt2 = 0;

  // prologue: prefetch step 0
  float4 ld[4];
  int labv;
  {
    const float4* src = (const float4*)(emb + base * DIM);
#pragma unroll
    for (int r = 0; r < 4; ++r) ld[r] = src[lane + 64 * r];
    labv = lab[base + (lane & 31)];
  }

  for (int step = 0; step < STEPS; ++step) {
    // stage current step into wave-private LDS, transposed [dim][point]
#pragma unroll
    for (int r = 0; r < 4; ++r) {
      const int i = lane + 64 * r;
      const int p = i >> 3, d0 = (i & 7) * 4;
      st[(d0 + 0) * 33 + p] = ld[r].x;
      st[(d0 + 1) * 33 + p] = ld[r].y;
      st[(d0 + 2) * 33 + p] = ld[r].z;
      st[(d0 + 3) * 33 + p] = ld[r].w;
    }
    const int labv_c = labv;

    // prefetch next step (overlaps with compute below)
    if (step < STEPS - 1) {
      const float4* src = (const float4*)(emb + (base + (step + 1) * 32) * DIM);
#pragma unroll
      for (int r = 0; r < 4; ++r) ld[r] = src[lane + 64 * r];
      labv = lab[base + (step + 1) * 32 + (lane & 31)];
    }

    // A fragments: one-hot, 3 label tiles; counts ride along as int adds
    bf16x8 a0, a1, a2;
#pragma unroll
    for (int j = 0; j < 8; ++j) {
      const int lj = __shfl(labv_c, g * 8 + j);
      const int h0 = (lj == m0), h1 = (lj == m0 + 16), h2 = (lj == m0 + 32);
      a0[j] = h0 ? (short)0x3F80 : (short)0;
      a1[j] = h1 ? (short)0x3F80 : (short)0;
      a2[j] = h2 ? (short)0x3F80 : (short)0;
      cnt0 += h0; cnt1 += h1; cnt2 += h2;
    }

    // B fragments: E[k][n] from LDS, n = m0 (+16), k = g*8+j
    bf16x8 b0, b1;
#pragma unroll
    for (int j = 0; j < 8; ++j) {
      b0[j] = f2bf(st[m0 * 33 + g * 8 + j]);
      b1[j] = f2bf(st[(m0 + 16) * 33 + g * 8 + j]);
    }

    acc[0][0] = __builtin_amdgcn_mfma_f32_16x16x32_bf16(a0, b0, acc[0][0], 0, 0, 0);
    acc[0][1] = __builtin_amdgcn_mfma_f32_16x16x32_bf16(a0, b1, acc[0][1], 0, 0, 0);
    acc[1][0] = __builtin_amdgcn_mfma_f32_16x16x32_bf16(a1, b0, acc[1][0], 0, 0, 0);
    acc[1][1] = __builtin_amdgcn_mfma_f32_16x16x32_bf16(a1, b1, acc[1][1], 0, 0, 0);
    acc[2][0] = __builtin_amdgcn_mfma_f32_16x16x32_bf16(a2, b0, acc[2][0], 0, 0, 0);
    acc[2][1] = __builtin_amdgcn_mfma_f32_16x16x32_bf16(a2, b1, acc[2][1], 0, 0, 0);
  }

  // counts: reduce across the 4 k-groups (lanes l, l+16, l+32, l+48)
  cnt0 += __shfl_xor(cnt0, 16); cnt0 += __shfl_xor(cnt0, 32);
  cnt1 += __shfl_xor(cnt1, 16); cnt1 += __shfl_xor(cnt1, 32);
  cnt2 += __shfl_xor(cnt2, 16); cnt2 += __shfl_xor(cnt2, 32);
  if (lane < 16)            s_cnt4[w][m0]      = cnt0;
  else if (lane < 32)       s_cnt4[w][m0 + 16] = cnt1;
  if (lane == 32)           s_cnt4[w][32]      = cnt2;

  // per-wave epilogue: dump accumulators into the (now free) staging buffer
  // as [label][dim]. D layout: row(label-in-tile) = g*4 + r, col = m0 (+16u).
#pragma unroll
  for (int t = 0; t < 2; ++t)
#pragma unroll
    for (int u = 0; u < 2; ++u)
#pragma unroll
      for (int r = 0; r < 4; ++r)
        st[(t * 16 + g * 4 + r) * DIM + m0 + 16 * u] = acc[t][u][r];
  if (lane < 16) {
    st[32 * DIM + m0]      = acc[2][0][0];
    st[32 * DIM + m0 + 16] = acc[2][1][0];
  }
  __syncthreads();

  // cross-wave reduce + global atomics (1056 + 33 per block)
  for (int i = tid; i < NLAB * DIM; i += 256) {
    const float v = s_stage[0][i] + s_stage[1][i] + s_stage[2][i] + s_stage[3][i];
    atomicAdd(&gsum[(size_t)b * (NLAB * DIM) + i], v);
  }
  if (tid < NLAB) {
    const int c = s_cnt4[0][tid] + s_cnt4[1][tid] + s_cnt4[2][tid] + s_cnt4[3][tid];
    atomicAdd(&gcnt[b * NLAB + tid], (float)c);
  }
}

// Pass 2: per-point hinge, weight-folded; one atomic per block.
// R7 post-mortem of R6: VGPR stayed 32 -> compiler SANK the batched loads
// back into the consume loop (source-order loops are no fence). This
// version pins the 16-load batch with sched_barrier(0) so all loads are
// issued before any use (forces ~32 VGPR of e[] to stay live), and
// distributes the sqrt/hinge tail across the 8 lanes of each sub
// (lane8==k handles iteration k; s[it] is sub-replicated post-reduce).
__global__ __launch_bounds__(256) void pass2_kernel(
    const float* __restrict__ emb, const int* __restrict__ lab,
    const float* __restrict__ gsum, const float* __restrict__ gcnt,
    float* __restrict__ pullb) {
  const int b   = blockIdx.y;
  const int tid = threadIdx.x;
  __shared__ __align__(16) float s_mean[NLAB * 36];
  __shared__ float s_w[NLAB];
  __shared__ float s_red[4];

  for (int i = tid; i < NLAB * DIM; i += 256) {
    const int l = i >> 5, d = i & 31;
    const float c = gcnt[b * NLAB + l];
    s_mean[l * 36 + d] = gsum[b * (NLAB * DIM) + i] / fmaxf(c, 1.0f);
  }
  if (tid < 64) {
    const float c = (tid < NLAB) ? gcnt[b * NLAB + tid] : 0.f;
    const int pres = (tid >= 1 && tid < NLAB && c > 0.f) ? 1 : 0;
    const unsigned long long bal = __ballot(pres);
    const float n_inst = (float)__popcll(bal);
    if (tid < NLAB)
      s_w[tid] = pres ? 1.f / (fmaxf(c, 1.f) * (n_inst + 1e-6f)) : 0.f;
  }
  __syncthreads();

  const int sub   = tid >> 3;
  const int lane8 = tid & 7;
  const int d0    = lane8 << 2;
  const size_t base = (size_t)b * NPTS;
  const int p0 = blockIdx.x * 32 + sub;
  constexpr int NIT     = NPTS / (BPB2 * 32);   // 8
  constexpr int PSTRIDE = BPB2 * 32;            // 16384

  // 1) issue ALL loads (8 labels + 8 float4s = 16 VMEM in flight),
  //    then FENCE so the compiler cannot sink them into the consume loop.
  int labs[NIT];
#pragma unroll
  for (int it = 0; it < NIT; ++it)
    labs[it] = lab[base + p0 + it * PSTRIDE];
  float4 e[NIT];
#pragma unroll
  for (int it = 0; it < NIT; ++it)
    e[it] = *(const float4*)(emb + (base + p0 + (size_t)it * PSTRIDE) * DIM + d0);
  __builtin_amdgcn_sched_barrier(0);

  // 2) LDS mean reads (label loads are the oldest VMEM -> ready first;
  //    e[] loads still in flight underneath) + per-lane partial SoS
  float s[NIT];
#pragma unroll
  for (int it = 0; it < NIT; ++it) {
    const float4 m = *(const float4*)(s_mean + labs[it] * 36 + d0);
    const float dx = e[it].x - m.x, dy = e[it].y - m.y;
    const float dz = e[it].z - m.z, dw = e[it].w - m.w;
    s[it] = dx * dx + dy * dy + dz * dz + dw * dw;
  }

  // 3) 8 independent 3-deep shuffle chains
#pragma unroll
  for (int it = 0; it < NIT; ++it) {
    s[it] += __shfl_xor(s[it], 1);
    s[it] += __shfl_xor(s[it], 2);
    s[it] += __shfl_xor(s[it], 4);
  }

  // 4) distribute tail: lane8==k handles iteration k (s[it] and labs[it]
  //    are identical across the sub's 8 lanes). Every lane: 1 sqrt + 1 LDS.
  float sv = s[0];
  int   lv = labs[0];
#pragma unroll
  for (int it = 1; it < NIT; ++it) {
    sv = (lane8 == it) ? s[it] : sv;
    lv = (lane8 == it) ? labs[it] : lv;
  }
  const float dist = sqrtf(sv + 1e-24f);
  float wacc = s_w[lv] * fmaxf(dist - 0.1f, 0.f);

#pragma unroll
  for (int m = 1; m < 64; m <<= 1) wacc += __shfl_xor(wacc, m);
  if ((tid & 63) == 0) s_red[tid >> 6] = wacc;
  __syncthreads();
  if (tid == 0)
    atomicAdd(&pullb[b], s_red[0] + s_red[1] + s_red[2] + s_red[3]);
}

// Per-batch push + final combine. One wave per batch, single block.
__global__ __launch_bounds__(512) void finish_kernel(
    const float* __restrict__ gsum, const float* __restrict__ gcnt,
    const float* __restrict__ pullb, float* __restrict__ out) {
  const int tid = threadIdx.x;
  const int b   = tid >> 6;
  const int t   = tid & 63;
  __shared__ __align__(16) float s_mn[BATCH * 32 * DIM];
  __shared__ float s_ps[BATCH];
  float* mn = s_mn + b * 32 * DIM;

  int pres = 0;
  if (t < 32) {
    const int l = t + 1;
    const float cnt = gcnt[b * NLAB + l];
    pres = (cnt > 0.f) ? 1 : 0;
    const float inv = 1.f / fmaxf(cnt, 1.f);
    float v[DIM];
    float n2 = 0.f;
    for (int d = 0; d < DIM; d++) {
      v[d] = gsum[b * (NLAB * DIM) + l * DIM + d] * inv;
      n2  += v[d] * v[d];
    }
    const float scale = 1.f / fmaxf(sqrtf(n2), 1e-12f);
    for (int d = 0; d < DIM; d++) mn[t * DIM + d] = v[d] * scale;
  }
  const unsigned long long bal = __ballot(pres);
  const unsigned int pmask32 = (unsigned int)(bal & 0xFFFFFFFFull);
  const int n_inst = __popc(pmask32);

  __syncthreads();

  float hp_sum = 0.f, pm_sum = 0.f;
  for (int idx = t; idx < 1024; idx += 64) {
    const int i = idx >> 5, j = idx & 31;
    if (j > i && ((pmask32 >> i) & 1u) && ((pmask32 >> j) & 1u)) {
      const float4* a = (const float4*)(mn + i * DIM);
      const float4* c = (const float4*)(mn + j * DIM);
      float sq = 0.f;
      for (int q = 0; q < 8; q++) {
        const float4 av = a[q], cv = c[q];
        const float dx = av.x - cv.x, dy = av.y - cv.y;
        const float dz = av.z - cv.z, dw = av.w - cv.w;
        sq += dx * dx + dy * dy + dz * dz + dw * dw;
      }
      const float dmat = sqrtf(sq + 1e-24f);
      hp_sum += fmaxf(1.0f - dmat, 0.f);   // 2*DELTA_D = 1.0
      pm_sum += 1.f;
    }
  }
  for (int m = 1; m < 64; m <<= 1) {
    hp_sum += __shfl_xor(hp_sum, m);
    pm_sum += __shfl_xor(pm_sum, m);
  }
  const float push = (n_inst > 1) ? hp_sum / (pm_sum + 1e-6f) : 0.f;
  if (t == 0) s_ps[b] = push;
  __syncthreads();

  if (tid < 64) {
    float pl = (t < BATCH) ? pullb[t] : 0.f;
    float ps = (t < BATCH) ? s_ps[t] : 0.f;
#pragma unroll
    for (int m = 1; m < 64; m <<= 1) {
      pl += __shfl_xor(pl, m);
      ps += __shfl_xor(ps, m);
    }
    if (t == 0) {
      const float pull_m = pl / (float)BATCH;
      const float push_m = ps / (float)BATCH;
      out[0] = pull_m + push_m;
      out[1] = pull_m;
      out[2] = push_m;
    }
  }
}

extern "C" void kernel_launch(void* const* d_in, const int* in_sizes, int n_in,
                              void* d_out, int out_size, void* d_ws, size_t ws_size,
                              hipStream_t stream) {
  const float* emb = (const float*)d_in[0];
  const int*   lab = (const int*)d_in[1];
  float* out = (float*)d_out;
  float* ws  = (float*)d_ws;

  float* gcnt  = ws + OFF_CNT;
  float* gsum  = ws + OFF_SUM;
  float* pullb = ws + OFF_PULL;

  hipMemsetAsync(d_ws, 0, WS_FLOATS * sizeof(float), stream);

  dim3 grid1(G1X, BATCH);
  dim3 grid2(BPB2, BATCH);
  pass1_kernel<<<grid1, 256, 0, stream>>>(emb, lab, gsum, gcnt);
  pass2_kernel<<<grid2, 256, 0, stream>>>(emb, lab, gsum, gcnt, pullb);
  finish_kernel<<<1, 512, 0, stream>>>(gsum, gcnt, pullb, out);
}

// Round 4
// 300.413 us; speedup vs baseline: 1.0214x; 1.0140x over previous
//
#include <hip/hip_runtime.h>
#include <hip/hip_bf16.h>

#define BATCH 8
#define NPTS  131072
#define DIM   32
#define NLAB  33
#define G1X   256             // pass1 blocks per batch -> 2048 total = 8/CU
#define P1PTS 512             // points per pass1 block (128 per wave, 4 steps)
#define BPB2  512             // pass2 blocks per batch

// ws float layout
#define OFF_CNT   0                    // BATCH*NLAB = 264
#define OFF_SUM   264                  // BATCH*NLAB*DIM = 8448
#define OFF_PULL  (264 + 8448)         // 8
#define WS_FLOATS (OFF_PULL + 8)

typedef short  bf16x8 __attribute__((ext_vector_type(8)));
typedef float  f32x4  __attribute__((ext_vector_type(4)));

static __device__ __forceinline__ short f2bf(float f) {
  __hip_bfloat16 h = __float2bfloat16(f);
  return *reinterpret_cast<short*>(&h);
}

// Pass 1: sums[l][d] = onehot(labels)^T @ E  via MFMA one-hot GEMM.
// Wave-private staging (no barriers in hot loop), one-hot A built from
// shuffled labels, 6 mfma_f32_16x16x32_bf16 per 32 points, counts from the
// compare bits. R6: 2048 blocks (P1PTS 512) for occupancy.
__global__ __launch_bounds__(256) void pass1_kernel(
    const float* __restrict__ emb, const int* __restrict__ lab,
    float* __restrict__ gsum, float* __restrict__ gcnt) {
  const int b    = blockIdx.y;
  const int tid  = threadIdx.x;
  const int w    = tid >> 6;
  const int lane = tid & 63;

  constexpr int STEPS = P1PTS / 128;   // 4: each wave = STEPS*32 points

  // wave-private transposed tile: st[d*33 + p], d=dim 0..31, p=point 0..31
  __shared__ float s_stage[4][32 * 33];   // 16.9 KB
  __shared__ int   s_cnt4[4][NLAB];
  float* st = s_stage[w];

  const size_t base = (size_t)b * NPTS + (size_t)blockIdx.x * P1PTS
                    + (size_t)w * (P1PTS / 4);

  const int m0 = lane & 15;      // A row (label within tile), B col (dim)
  const int g  = lane >> 4;      // k-group
  f32x4 acc[3][2];
#pragma unroll
  for (int t = 0; t < 3; ++t)
#pragma unroll
    for (int u = 0; u < 2; ++u) acc[t][u] = (f32x4){0.f, 0.f, 0.f, 0.f};
  int cnt0 = 0, cnt1 = 0, cnt2 = 0;

  // prologue: prefetch step 0
  float4 ld[4];
  int labv;
  {
    const float4* src = (const float4*)(emb + base * DIM);
#pragma unroll
    for (int r = 0; r < 4; ++r) ld[r] = src[lane + 64 * r];
    labv = lab[base + (lane & 31)];
  }

  for (int step = 0; step < STEPS; ++step) {
    // stage current step into wave-private LDS, transposed [dim][point]
#pragma unroll
    for (int r = 0; r < 4; ++r) {
      const int i = lane + 64 * r;
      const int p = i >> 3, d0 = (i & 7) * 4;
      st[(d0 + 0) * 33 + p] = ld[r].x;
      st[(d0 + 1) * 33 + p] = ld[r].y;
      st[(d0 + 2) * 33 + p] = ld[r].z;
      st[(d0 + 3) * 33 + p] = ld[r].w;
    }
    const int labv_c = labv;

    // prefetch next step (overlaps with compute below)
    if (step < STEPS - 1) {
      const float4* src = (const float4*)(emb + (base + (step + 1) * 32) * DIM);
#pragma unroll
      for (int r = 0; r < 4; ++r) ld[r] = src[lane + 64 * r];
      labv = lab[base + (step + 1) * 32 + (lane & 31)];
    }

    // A fragments: one-hot, 3 label tiles; counts ride along as int adds
    bf16x8 a0, a1, a2;
#pragma unroll
    for (int j = 0; j < 8; ++j) {
      const int lj = __shfl(labv_c, g * 8 + j);
      const int h0 = (lj == m0), h1 = (lj == m0 + 16), h2 = (lj == m0 + 32);
      a0[j] = h0 ? (short)0x3F80 : (short)0;
      a1[j] = h1 ? (short)0x3F80 : (short)0;
      a2[j] = h2 ? (short)0x3F80 : (short)0;
      cnt0 += h0; cnt1 += h1; cnt2 += h2;
    }

    // B fragments: E[k][n] from LDS, n = m0 (+16), k = g*8+j
    bf16x8 b0, b1;
#pragma unroll
    for (int j = 0; j < 8; ++j) {
      b0[j] = f2bf(st[m0 * 33 + g * 8 + j]);
      b1[j] = f2bf(st[(m0 + 16) * 33 + g * 8 + j]);
    }

    acc[0][0] = __builtin_amdgcn_mfma_f32_16x16x32_bf16(a0, b0, acc[0][0], 0, 0, 0);
    acc[0][1] = __builtin_amdgcn_mfma_f32_16x16x32_bf16(a0, b1, acc[0][1], 0, 0, 0);
    acc[1][0] = __builtin_amdgcn_mfma_f32_16x16x32_bf16(a1, b0, acc[1][0], 0, 0, 0);
    acc[1][1] = __builtin_amdgcn_mfma_f32_16x16x32_bf16(a1, b1, acc[1][1], 0, 0, 0);
    acc[2][0] = __builtin_amdgcn_mfma_f32_16x16x32_bf16(a2, b0, acc[2][0], 0, 0, 0);
    acc[2][1] = __builtin_amdgcn_mfma_f32_16x16x32_bf16(a2, b1, acc[2][1], 0, 0, 0);
  }

  // counts: reduce across the 4 k-groups (lanes l, l+16, l+32, l+48)
  cnt0 += __shfl_xor(cnt0, 16); cnt0 += __shfl_xor(cnt0, 32);
  cnt1 += __shfl_xor(cnt1, 16); cnt1 += __shfl_xor(cnt1, 32);
  cnt2 += __shfl_xor(cnt2, 16); cnt2 += __shfl_xor(cnt2, 32);
  if (lane < 16)            s_cnt4[w][m0]      = cnt0;
  else if (lane < 32)       s_cnt4[w][m0 + 16] = cnt1;
  if (lane == 32)           s_cnt4[w][32]      = cnt2;

  // per-wave epilogue: dump accumulators into the (now free) staging buffer
  // as [label][dim]. D layout: row(label-in-tile) = g*4 + r, col = m0 (+16u).
#pragma unroll
  for (int t = 0; t < 2; ++t)
#pragma unroll
    for (int u = 0; u < 2; ++u)
#pragma unroll
      for (int r = 0; r < 4; ++r)
        st[(t * 16 + g * 4 + r) * DIM + m0 + 16 * u] = acc[t][u][r];
  if (lane < 16) {
    st[32 * DIM + m0]      = acc[2][0][0];
    st[32 * DIM + m0 + 16] = acc[2][1][0];
  }
  __syncthreads();

  // cross-wave reduce + global atomics (1056 + 33 per block)
  for (int i = tid; i < NLAB * DIM; i += 256) {
    const float v = s_stage[0][i] + s_stage[1][i] + s_stage[2][i] + s_stage[3][i];
    atomicAdd(&gsum[(size_t)b * (NLAB * DIM) + i], v);
  }
  if (tid < NLAB) {
    const int c = s_cnt4[0][tid] + s_cnt4[1][tid] + s_cnt4[2][tid] + s_cnt4[3][tid];
    atomicAdd(&gcnt[b * NLAB + tid], (float)c);
  }
}

// Pass 2: per-point hinge, weight-folded; one atomic per block.
// R8 post-mortem of R7: sched_barrier(0) did NOT pin the load batch
// (VGPR 28) -- the sinking is IR-level (loads are speculatable across the
// intrinsic), not MachineScheduler-level. This version issues the 16 loads
// as asm volatile (un-sinkable, un-splittable), overlaps the LDS mean
// gather with the 8 in-flight embedding loads via counted s_waitcnt
// vmcnt(8), and fences every waitcnt with sched_barrier(0) (rule: hipcc
// hoists register-only consumers past inline-asm waitcnt otherwise).
__global__ __launch_bounds__(256, 4) void pass2_kernel(
    const float* __restrict__ emb, const int* __restrict__ lab,
    const float* __restrict__ gsum, const float* __restrict__ gcnt,
    float* __restrict__ pullb) {
  const int b   = blockIdx.y;
  const int tid = threadIdx.x;
  __shared__ __align__(16) float s_mean[NLAB * 36];
  __shared__ float s_w[NLAB];
  __shared__ float s_red[4];

  for (int i = tid; i < NLAB * DIM; i += 256) {
    const int l = i >> 5, d = i & 31;
    const float c = gcnt[b * NLAB + l];
    s_mean[l * 36 + d] = gsum[b * (NLAB * DIM) + i] / fmaxf(c, 1.0f);
  }
  if (tid < 64) {
    const float c = (tid < NLAB) ? gcnt[b * NLAB + tid] : 0.f;
    const int pres = (tid >= 1 && tid < NLAB && c > 0.f) ? 1 : 0;
    const unsigned long long bal = __ballot(pres);
    const float n_inst = (float)__popcll(bal);
    if (tid < NLAB)
      s_w[tid] = pres ? 1.f / (fmaxf(c, 1.f) * (n_inst + 1e-6f)) : 0.f;
  }
  __syncthreads();   // drains vmcnt to 0: our counted waits below are exact

  const int sub   = tid >> 3;
  const int lane8 = tid & 7;
  const int d0    = lane8 << 2;
  const size_t base = (size_t)b * NPTS;
  const int p0 = blockIdx.x * 32 + sub;
  constexpr int NIT     = NPTS / (BPB2 * 32);   // 8
  constexpr int PSTRIDE = BPB2 * 32;            // 16384

  // ---- issue ALL 16 loads via asm volatile: 8 labels first, then 8 embs.
  int   labs[NIT];
  f32x4 e[NIT];
#pragma unroll
  for (int it = 0; it < NIT; ++it) {
    const unsigned long long al =
        (unsigned long long)(lab + base + p0 + (size_t)it * PSTRIDE);
    asm volatile("global_load_dword %0, %1, off"
                 : "=&v"(labs[it]) : "v"(al));
  }
#pragma unroll
  for (int it = 0; it < NIT; ++it) {
    const unsigned long long ae =
        (unsigned long long)(emb + (base + p0 + (size_t)it * PSTRIDE) * DIM + d0);
    asm volatile("global_load_dwordx4 %0, %1, off"
                 : "=&v"(e[it]) : "v"(ae));
  }
  __builtin_amdgcn_sched_barrier(0);

  // ---- labels ready (8 emb loads still in flight) -> gather means from LDS
  asm volatile("s_waitcnt vmcnt(8)" ::: "memory");
  __builtin_amdgcn_sched_barrier(0);
  f32x4 m[NIT];
#pragma unroll
  for (int it = 0; it < NIT; ++it)
    m[it] = *(const f32x4*)(s_mean + labs[it] * 36 + d0);
  __builtin_amdgcn_sched_barrier(0);

  // ---- embeddings ready -> compute
  asm volatile("s_waitcnt vmcnt(0)" ::: "memory");
  __builtin_amdgcn_sched_barrier(0);

  float s[NIT];
#pragma unroll
  for (int it = 0; it < NIT; ++it) {
    const float dx = e[it][0] - m[it][0], dy = e[it][1] - m[it][1];
    const float dz = e[it][2] - m[it][2], dw = e[it][3] - m[it][3];
    s[it] = dx * dx + dy * dy + dz * dz + dw * dw;
  }

  // 8 independent 3-deep shuffle chains
#pragma unroll
  for (int it = 0; it < NIT; ++it) {
    s[it] += __shfl_xor(s[it], 1);
    s[it] += __shfl_xor(s[it], 2);
    s[it] += __shfl_xor(s[it], 4);
  }

  // distribute tail: lane8==k handles iteration k (s[it], labs[it] are
  // sub-replicated post-reduce). Every lane: 1 sqrt + 1 LDS read.
  float sv = s[0];
  int   lv = labs[0];
#pragma unroll
  for (int it = 1; it < NIT; ++it) {
    sv = (lane8 == it) ? s[it] : sv;
    lv = (lane8 == it) ? labs[it] : lv;
  }
  const float dist = sqrtf(sv + 1e-24f);
  float wacc = s_w[lv] * fmaxf(dist - 0.1f, 0.f);

#pragma unroll
  for (int mm = 1; mm < 64; mm <<= 1) wacc += __shfl_xor(wacc, mm);
  if ((tid & 63) == 0) s_red[tid >> 6] = wacc;
  __syncthreads();
  if (tid == 0)
    atomicAdd(&pullb[b], s_red[0] + s_red[1] + s_red[2] + s_red[3]);
}

// Per-batch push + final combine. One wave per batch, single block.
__global__ __launch_bounds__(512) void finish_kernel(
    const float* __restrict__ gsum, const float* __restrict__ gcnt,
    const float* __restrict__ pullb, float* __restrict__ out) {
  const int tid = threadIdx.x;
  const int b   = tid >> 6;
  const int t   = tid & 63;
  __shared__ __align__(16) float s_mn[BATCH * 32 * DIM];
  __shared__ float s_ps[BATCH];
  float* mn = s_mn + b * 32 * DIM;

  int pres = 0;
  if (t < 32) {
    const int l = t + 1;
    const float cnt = gcnt[b * NLAB + l];
    pres = (cnt > 0.f) ? 1 : 0;
    const float inv = 1.f / fmaxf(cnt, 1.f);
    float v[DIM];
    float n2 = 0.f;
    for (int d = 0; d < DIM; d++) {
      v[d] = gsum[b * (NLAB * DIM) + l * DIM + d] * inv;
      n2  += v[d] * v[d];
    }
    const float scale = 1.f / fmaxf(sqrtf(n2), 1e-12f);
    for (int d = 0; d < DIM; d++) mn[t * DIM + d] = v[d] * scale;
  }
  const unsigned long long bal = __ballot(pres);
  const unsigned int pmask32 = (unsigned int)(bal & 0xFFFFFFFFull);
  const int n_inst = __popc(pmask32);

  __syncthreads();

  float hp_sum = 0.f, pm_sum = 0.f;
  for (int idx = t; idx < 1024; idx += 64) {
    const int i = idx >> 5, j = idx & 31;
    if (j > i && ((pmask32 >> i) & 1u) && ((pmask32 >> j) & 1u)) {
      const float4* a = (const float4*)(mn + i * DIM);
      const float4* c = (const float4*)(mn + j * DIM);
      float sq = 0.f;
      for (int q = 0; q < 8; q++) {
        const float4 av = a[q], cv = c[q];
        const float dx = av.x - cv.x, dy = av.y - cv.y;
        const float dz = av.z - cv.z, dw = av.w - cv.w;
        sq += dx * dx + dy * dy + dz * dz + dw * dw;
      }
      const float dmat = sqrtf(sq + 1e-24f);
      hp_sum += fmaxf(1.0f - dmat, 0.f);   // 2*DELTA_D = 1.0
      pm_sum += 1.f;
    }
  }
  for (int m = 1; m < 64; m <<= 1) {
    hp_sum += __shfl_xor(hp_sum, m);
    pm_sum += __shfl_xor(pm_sum, m);
  }
  const float push = (n_inst > 1) ? hp_sum / (pm_sum + 1e-6f) : 0.f;
  if (t == 0) s_ps[b] = push;
  __syncthreads();

  if (tid < 64) {
    float pl = (t < BATCH) ? pullb[t] : 0.f;
    float ps = (t < BATCH) ? s_ps[t] : 0.f;
#pragma unroll
    for (int m = 1; m < 64; m <<= 1) {
      pl += __shfl_xor(pl, m);
      ps += __shfl_xor(ps, m);
    }
    if (t == 0) {
      const float pull_m = pl / (float)BATCH;
      const float push_m = ps / (float)BATCH;
      out[0] = pull_m + push_m;
      out[1] = pull_m;
      out[2] = push_m;
    }
  }
}

extern "C" void kernel_launch(void* const* d_in, const int* in_sizes, int n_in,
                              void* d_out, int out_size, void* d_ws, size_t ws_size,
                              hipStream_t stream) {
  const float* emb = (const float*)d_in[0];
  const int*   lab = (const int*)d_in[1];
  float* out = (float*)d_out;
  float* ws  = (float*)d_ws;

  float* gcnt  = ws + OFF_CNT;
  float* gsum  = ws + OFF_SUM;
  float* pullb = ws + OFF_PULL;

  hipMemsetAsync(d_ws, 0, WS_FLOATS * sizeof(float), stream);

  dim3 grid1(G1X, BATCH);
  dim3 grid2(BPB2, BATCH);
  pass1_kernel<<<grid1, 256, 0, stream>>>(emb, lab, gsum, gcnt);
  pass2_kernel<<<grid2, 256, 0, stream>>>(emb, lab, gsum, gcnt, pullb);
  finish_kernel<<<1, 512, 0, stream>>>(gsum, gcnt, pullb, out);
}

// Round 5
// 240.245 us; speedup vs baseline: 1.2773x; 1.2504x over previous
//
#include <hip/hip_runtime.h>
#include <hip/hip_bf16.h>

#define BATCH 8
#define NPTS  131072
#define DIM   32
#define NLAB  33
#define G1X   256             // pass1 blocks per batch -> 2048 total = 8/CU
#define P1PTS 512             // points per pass1 block (128 per wave, 4 steps)
#define BPB2  128             // pass2 blocks per batch (R9: 512->128, fatter blocks)

// ws float layout
#define OFF_CNT   0                    // BATCH*NLAB = 264
#define OFF_SUM   264                  // BATCH*NLAB*DIM = 8448
#define OFF_PULL  (264 + 8448)         // BATCH*BPB2 = 1024 per-block partials
#define WS_FLOATS (OFF_PULL + BATCH * BPB2)

typedef short  bf16x8 __attribute__((ext_vector_type(8)));
typedef float  f32x4  __attribute__((ext_vector_type(4)));

static __device__ __forceinline__ short f2bf(float f) {
  __hip_bfloat16 h = __float2bfloat16(f);
  return *reinterpret_cast<short*>(&h);
}

// Pass 1: sums[l][d] = onehot(labels)^T @ E  via MFMA one-hot GEMM.
// UNCHANGED this round (control; will get its counters once pass2 drops).
__global__ __launch_bounds__(256) void pass1_kernel(
    const float* __restrict__ emb, const int* __restrict__ lab,
    float* __restrict__ gsum, float* __restrict__ gcnt) {
  const int b    = blockIdx.y;
  const int tid  = threadIdx.x;
  const int w    = tid >> 6;
  const int lane = tid & 63;

  constexpr int STEPS = P1PTS / 128;   // 4: each wave = STEPS*32 points

  __shared__ float s_stage[4][32 * 33];   // 16.9 KB
  __shared__ int   s_cnt4[4][NLAB];
  float* st = s_stage[w];

  const size_t base = (size_t)b * NPTS + (size_t)blockIdx.x * P1PTS
                    + (size_t)w * (P1PTS / 4);

  const int m0 = lane & 15;      // A row (label within tile), B col (dim)
  const int g  = lane >> 4;      // k-group
  f32x4 acc[3][2];
#pragma unroll
  for (int t = 0; t < 3; ++t)
#pragma unroll
    for (int u = 0; u < 2; ++u) acc[t][u] = (f32x4){0.f, 0.f, 0.f, 0.f};
  int cnt0 = 0, cnt1 = 0, cnt2 = 0;

  // prologue: prefetch step 0
  float4 ld[4];
  int labv;
  {
    const float4* src = (const float4*)(emb + base * DIM);
#pragma unroll
    for (int r = 0; r < 4; ++r) ld[r] = src[lane + 64 * r];
    labv = lab[base + (lane & 31)];
  }

  for (int step = 0; step < STEPS; ++step) {
#pragma unroll
    for (int r = 0; r < 4; ++r) {
      const int i = lane + 64 * r;
      const int p = i >> 3, d0 = (i & 7) * 4;
      st[(d0 + 0) * 33 + p] = ld[r].x;
      st[(d0 + 1) * 33 + p] = ld[r].y;
      st[(d0 + 2) * 33 + p] = ld[r].z;
      st[(d0 + 3) * 33 + p] = ld[r].w;
    }
    const int labv_c = labv;

    if (step < STEPS - 1) {
      const float4* src = (const float4*)(emb + (base + (step + 1) * 32) * DIM);
#pragma unroll
      for (int r = 0; r < 4; ++r) ld[r] = src[lane + 64 * r];
      labv = lab[base + (step + 1) * 32 + (lane & 31)];
    }

    bf16x8 a0, a1, a2;
#pragma unroll
    for (int j = 0; j < 8; ++j) {
      const int lj = __shfl(labv_c, g * 8 + j);
      const int h0 = (lj == m0), h1 = (lj == m0 + 16), h2 = (lj == m0 + 32);
      a0[j] = h0 ? (short)0x3F80 : (short)0;
      a1[j] = h1 ? (short)0x3F80 : (short)0;
      a2[j] = h2 ? (short)0x3F80 : (short)0;
      cnt0 += h0; cnt1 += h1; cnt2 += h2;
    }

    bf16x8 b0, b1;
#pragma unroll
    for (int j = 0; j < 8; ++j) {
      b0[j] = f2bf(st[m0 * 33 + g * 8 + j]);
      b1[j] = f2bf(st[(m0 + 16) * 33 + g * 8 + j]);
    }

    acc[0][0] = __builtin_amdgcn_mfma_f32_16x16x32_bf16(a0, b0, acc[0][0], 0, 0, 0);
    acc[0][1] = __builtin_amdgcn_mfma_f32_16x16x32_bf16(a0, b1, acc[0][1], 0, 0, 0);
    acc[1][0] = __builtin_amdgcn_mfma_f32_16x16x32_bf16(a1, b0, acc[1][0], 0, 0, 0);
    acc[1][1] = __builtin_amdgcn_mfma_f32_16x16x32_bf16(a1, b1, acc[1][1], 0, 0, 0);
    acc[2][0] = __builtin_amdgcn_mfma_f32_16x16x32_bf16(a2, b0, acc[2][0], 0, 0, 0);
    acc[2][1] = __builtin_amdgcn_mfma_f32_16x16x32_bf16(a2, b1, acc[2][1], 0, 0, 0);
  }

  cnt0 += __shfl_xor(cnt0, 16); cnt0 += __shfl_xor(cnt0, 32);
  cnt1 += __shfl_xor(cnt1, 16); cnt1 += __shfl_xor(cnt1, 32);
  cnt2 += __shfl_xor(cnt2, 16); cnt2 += __shfl_xor(cnt2, 32);
  if (lane < 16)            s_cnt4[w][m0]      = cnt0;
  else if (lane < 32)       s_cnt4[w][m0 + 16] = cnt1;
  if (lane == 32)           s_cnt4[w][32]      = cnt2;

#pragma unroll
  for (int t = 0; t < 2; ++t)
#pragma unroll
    for (int u = 0; u < 2; ++u)
#pragma unroll
      for (int r = 0; r < 4; ++r)
        st[(t * 16 + g * 4 + r) * DIM + m0 + 16 * u] = acc[t][u][r];
  if (lane < 16) {
    st[32 * DIM + m0]      = acc[2][0][0];
    st[32 * DIM + m0 + 16] = acc[2][1][0];
  }
  __syncthreads();

  for (int i = tid; i < NLAB * DIM; i += 256) {
    const float v = s_stage[0][i] + s_stage[1][i] + s_stage[2][i] + s_stage[3][i];
    atomicAdd(&gsum[(size_t)b * (NLAB * DIM) + i], v);
  }
  if (tid < NLAB) {
    const int c = s_cnt4[0][tid] + s_cnt4[1][tid] + s_cnt4[2][tid] + s_cnt4[3][tid];
    atomicAdd(&gcnt[b * NLAB + tid], (float)c);
  }
}

// Pass 2: per-point hinge, streaming pipeline, NO ATOMICS.
// R9 post-mortem of R8: load batch finally pinned (VGPR 40) yet dur barely
// moved (97->92): per-wave MLP was NOT the dominant term. Remaining shared
// structure at the ~85us floor: 4096 blocks x {preamble(1089 L2 reads +
// 2 barriers) + 1 device-scope atomicAdd into ONE 32B line (pullb[0..7])
// ping-ponged across 8 non-coherent XCD L2s}. This version: (1) per-block
// partial via plain store to unique slot (zero atomics), (2) 4x fatter
// blocks (BPB2 128, 1024 pts/block) amortizing the preamble, (3) chunked
// double-buffered asm-volatile load pipeline (named A/B sets, rule #20)
// with counted vmcnt(16) so 16 loads stay in flight continuously.
#define CN 8                       // points per chunk
#define P2_ISSUE(LB, EB, C)                                                   \
  {                                                                           \
    _Pragma("unroll")                                                         \
    for (int j = 0; j < CN; ++j) {                                            \
      const size_t it = (size_t)(C) * CN + j;                                 \
      const unsigned long long al =                                           \
          (unsigned long long)(lab + base + p0 + it * PSTRIDE);               \
      asm volatile("global_load_dword %0, %1, off" : "=&v"(LB[j]) : "v"(al)); \
    }                                                                         \
    _Pragma("unroll")                                                         \
    for (int j = 0; j < CN; ++j) {                                            \
      const size_t it = (size_t)(C) * CN + j;                                 \
      const unsigned long long ae =                                           \
          (unsigned long long)(emb + (base + p0 + it * PSTRIDE) * DIM + d0);  \
      asm volatile("global_load_dwordx4 %0, %1, off" : "=&v"(EB[j]) : "v"(ae)); \
    }                                                                         \
  }

#define P2_COMPUTE(LB, EB)                                                    \
  {                                                                           \
    float s[CN];                                                              \
    _Pragma("unroll")                                                         \
    for (int j = 0; j < CN; ++j) {                                            \
      const f32x4 mv = *(const f32x4*)(s_mean + LB[j] * 36 + d0);             \
      const float dx = EB[j][0] - mv[0], dy = EB[j][1] - mv[1];               \
      const float dz = EB[j][2] - mv[2], dw = EB[j][3] - mv[3];               \
      s[j] = dx * dx + dy * dy + dz * dz + dw * dw;                           \
    }                                                                         \
    _Pragma("unroll")                                                         \
    for (int j = 0; j < CN; ++j) {                                            \
      s[j] += __shfl_xor(s[j], 1);                                            \
      s[j] += __shfl_xor(s[j], 2);                                            \
      s[j] += __shfl_xor(s[j], 4);                                            \
    }                                                                         \
    float sv = s[0];                                                          \
    int   lv = LB[0];                                                         \
    _Pragma("unroll")                                                         \
    for (int j = 1; j < CN; ++j) {                                            \
      sv = (lane8 == j) ? s[j] : sv;                                          \
      lv = (lane8 == j) ? LB[j] : lv;                                         \
    }                                                                         \
    const float dist = sqrtf(sv + 1e-24f);                                    \
    wacc += s_w[lv] * fmaxf(dist - 0.1f, 0.f);                                \
  }

__global__ __launch_bounds__(256, 4) void pass2_kernel(
    const float* __restrict__ emb, const int* __restrict__ lab,
    const float* __restrict__ gsum, const float* __restrict__ gcnt,
    float* __restrict__ pull_part) {
  const int b   = blockIdx.y;
  const int tid = threadIdx.x;
  __shared__ __align__(16) float s_mean[NLAB * 36];
  __shared__ float s_w[NLAB];
  __shared__ float s_red[4];

  for (int i = tid; i < NLAB * DIM; i += 256) {
    const int l = i >> 5, d = i & 31;
    const float c = gcnt[b * NLAB + l];
    s_mean[l * 36 + d] = gsum[b * (NLAB * DIM) + i] / fmaxf(c, 1.0f);
  }
  if (tid < 64) {
    const float c = (tid < NLAB) ? gcnt[b * NLAB + tid] : 0.f;
    const int pres = (tid >= 1 && tid < NLAB && c > 0.f) ? 1 : 0;
    const unsigned long long bal = __ballot(pres);
    const float n_inst = (float)__popcll(bal);
    if (tid < NLAB)
      s_w[tid] = pres ? 1.f / (fmaxf(c, 1.f) * (n_inst + 1e-6f)) : 0.f;
  }
  __syncthreads();   // drains vmcnt to 0: counted waits below are exact

  const int sub   = tid >> 3;
  const int lane8 = tid & 7;
  const int d0    = lane8 << 2;
  const size_t base = (size_t)b * NPTS;
  const int p0 = blockIdx.x * 32 + sub;
  constexpr int PSTRIDE = BPB2 * 32;            // 4096
  constexpr int NIT     = NPTS / PSTRIDE;       // 32 iterations / thread
  constexpr int NCH     = NIT / CN;             // 4 chunks

  int   labsA[CN], labsB[CN];
  f32x4 eA[CN], eB[CN];
  float wacc = 0.f;

  P2_ISSUE(labsA, eA, 0);
#pragma unroll
  for (int cc = 0; cc < NCH; cc += 2) {
    if (cc + 1 < NCH) P2_ISSUE(labsB, eB, cc + 1);
    if (cc + 1 < NCH) { asm volatile("s_waitcnt vmcnt(16)" ::: "memory"); }
    else              { asm volatile("s_waitcnt vmcnt(0)"  ::: "memory"); }
    __builtin_amdgcn_sched_barrier(0);
    P2_COMPUTE(labsA, eA);
    if (cc + 1 < NCH) {
      if (cc + 2 < NCH) P2_ISSUE(labsA, eA, cc + 2);
      if (cc + 2 < NCH) { asm volatile("s_waitcnt vmcnt(16)" ::: "memory"); }
      else              { asm volatile("s_waitcnt vmcnt(0)"  ::: "memory"); }
      __builtin_amdgcn_sched_barrier(0);
      P2_COMPUTE(labsB, eB);
    }
  }

#pragma unroll
  for (int mm = 1; mm < 64; mm <<= 1) wacc += __shfl_xor(wacc, mm);
  if ((tid & 63) == 0) s_red[tid >> 6] = wacc;
  __syncthreads();
  if (tid == 0)
    pull_part[b * BPB2 + blockIdx.x] =
        s_red[0] + s_red[1] + s_red[2] + s_red[3];
}

// Per-batch push + final combine. One wave per batch, single block.
// R9: also reduces the BPB2 per-block pull partials (replaces atomics).
__global__ __launch_bounds__(512) void finish_kernel(
    const float* __restrict__ gsum, const float* __restrict__ gcnt,
    const float* __restrict__ pull_part, float* __restrict__ out) {
  const int tid = threadIdx.x;
  const int b   = tid >> 6;
  const int t   = tid & 63;
  __shared__ __align__(16) float s_mn[BATCH * 32 * DIM];
  __shared__ float s_ps[BATCH];
  __shared__ float s_pl[BATCH];
  float* mn = s_mn + b * 32 * DIM;

  // pull: wave b reduces its BPB2(=128) block partials
  {
    float plsum = pull_part[b * BPB2 + t] + pull_part[b * BPB2 + 64 + t];
#pragma unroll
    for (int m = 1; m < 64; m <<= 1) plsum += __shfl_xor(plsum, m);
    if (t == 0) s_pl[b] = plsum;
  }

  int pres = 0;
  if (t < 32) {
    const int l = t + 1;
    const float cnt = gcnt[b * NLAB + l];
    pres = (cnt > 0.f) ? 1 : 0;
    const float inv = 1.f / fmaxf(cnt, 1.f);
    float v[DIM];
    float n2 = 0.f;
    for (int d = 0; d < DIM; d++) {
      v[d] = gsum[b * (NLAB * DIM) + l * DIM + d] * inv;
      n2  += v[d] * v[d];
    }
    const float scale = 1.f / fmaxf(sqrtf(n2), 1e-12f);
    for (int d = 0; d < DIM; d++) mn[t * DIM + d] = v[d] * scale;
  }
  const unsigned long long bal = __ballot(pres);
  const unsigned int pmask32 = (unsigned int)(bal & 0xFFFFFFFFull);
  const int n_inst = __popc(pmask32);

  __syncthreads();

  float hp_sum = 0.f, pm_sum = 0.f;
  for (int idx = t; idx < 1024; idx += 64) {
    const int i = idx >> 5, j = idx & 31;
    if (j > i && ((pmask32 >> i) & 1u) && ((pmask32 >> j) & 1u)) {
      const float4* a = (const float4*)(mn + i * DIM);
      const float4* c = (const float4*)(mn + j * DIM);
      float sq = 0.f;
      for (int q = 0; q < 8; q++) {
        const float4 av = a[q], cv = c[q];
        const float dx = av.x - cv.x, dy = av.y - cv.y;
        const float dz = av.z - cv.z, dw = av.w - cv.w;
        sq += dx * dx + dy * dy + dz * dz + dw * dw;
      }
      const float dmat = sqrtf(sq + 1e-24f);
      hp_sum += fmaxf(1.0f - dmat, 0.f);   // 2*DELTA_D = 1.0
      pm_sum += 1.f;
    }
  }
  for (int m = 1; m < 64; m <<= 1) {
    hp_sum += __shfl_xor(hp_sum, m);
    pm_sum += __shfl_xor(pm_sum, m);
  }
  const float push = (n_inst > 1) ? hp_sum / (pm_sum + 1e-6f) : 0.f;
  if (t == 0) s_ps[b] = push;
  __syncthreads();

  if (tid < 64) {
    float pl = (t < BATCH) ? s_pl[t] : 0.f;
    float ps = (t < BATCH) ? s_ps[t] : 0.f;
#pragma unroll
    for (int m = 1; m < 64; m <<= 1) {
      pl += __shfl_xor(pl, m);
      ps += __shfl_xor(ps, m);
    }
    if (t == 0) {
      const float pull_m = pl / (float)BATCH;
      const float push_m = ps / (float)BATCH;
      out[0] = pull_m + push_m;
      out[1] = pull_m;
      out[2] = push_m;
    }
  }
}

extern "C" void kernel_launch(void* const* d_in, const int* in_sizes, int n_in,
                              void* d_out, int out_size, void* d_ws, size_t ws_size,
                              hipStream_t stream) {
  const float* emb = (const float*)d_in[0];
  const int*   lab = (const int*)d_in[1];
  float* out = (float*)d_out;
  float* ws  = (float*)d_ws;

  float* gcnt  = ws + OFF_CNT;
  float* gsum  = ws + OFF_SUM;
  float* pullp = ws + OFF_PULL;

  hipMemsetAsync(d_ws, 0, WS_FLOATS * sizeof(float), stream);

  dim3 grid1(G1X, BATCH);
  dim3 grid2(BPB2, BATCH);
  pass1_kernel<<<grid1, 256, 0, stream>>>(emb, lab, gsum, gcnt);
  pass2_kernel<<<grid2, 256, 0, stream>>>(emb, lab, gsum, gcnt, pullp);
  finish_kernel<<<1, 512, 0, stream>>>(gsum, gcnt, pullp, out);
}

// Round 6
// 237.135 us; speedup vs baseline: 1.2940x; 1.0131x over previous
//
#include <hip/hip_runtime.h>
#include <hip/hip_bf16.h>

#define BATCH 8
#define NPTS  131072
#define DIM   32
#define NLAB  33
#define G1X   256             // pass1 blocks per batch -> 2048 total = 8/CU
#define P1PTS 512             // points per pass1 block (128 per wave, 4 steps)
#define BPB2  128             // pass2 blocks per batch

// ws float layout
#define OFF_CNT   0                                   // gcnt: BATCH*NLAB = 264
#define OFF_SUM   264                                 // gsum: BATCH*NLAB*DIM = 8448
#define OFF_PULL  (264 + 8448)                        // pull partials: BATCH*BPB2 = 1024
#define OFF_PSUM  (OFF_PULL + BATCH * BPB2)           // pass1 sum partials: 8*256*1056
#define OFF_PCNT  (OFF_PSUM + BATCH * G1X * NLAB * DIM)  // pass1 cnt partials: 8*256*33
#define WS_FLOATS (OFF_PCNT + BATCH * G1X * NLAB)

typedef short  bf16x8 __attribute__((ext_vector_type(8)));
typedef float  f32x4  __attribute__((ext_vector_type(4)));

static __device__ __forceinline__ short f2bf(float f) {
  __hip_bfloat16 h = __float2bfloat16(f);
  return *reinterpret_cast<short*>(&h);
}

// Pass 1: sums[l][d] = onehot(labels)^T @ E  via MFMA one-hot GEMM.
// R10: epilogue atomics REMOVED (was 2048 blocks x 1089 device atomicAdds
// into 8.7KB -> ~4096 serialized RMWs per cache line, the latency tail
// behind pass1's idle-pipes profile). Blocks now plain-store partials to
// unique slots; reduce_kernel folds them.
__global__ __launch_bounds__(256) void pass1_kernel(
    const float* __restrict__ emb, const int* __restrict__ lab,
    float* __restrict__ psum, float* __restrict__ pcnt) {
  const int b    = blockIdx.y;
  const int tid  = threadIdx.x;
  const int w    = tid >> 6;
  const int lane = tid & 63;

  constexpr int STEPS = P1PTS / 128;   // 4: each wave = STEPS*32 points

  __shared__ float s_stage[4][32 * 33];   // 16.9 KB
  __shared__ int   s_cnt4[4][NLAB];
  float* st = s_stage[w];

  const size_t base = (size_t)b * NPTS + (size_t)blockIdx.x * P1PTS
                    + (size_t)w * (P1PTS / 4);

  const int m0 = lane & 15;      // A row (label within tile), B col (dim)
  const int g  = lane >> 4;      // k-group
  f32x4 acc[3][2];
#pragma unroll
  for (int t = 0; t < 3; ++t)
#pragma unroll
    for (int u = 0; u < 2; ++u) acc[t][u] = (f32x4){0.f, 0.f, 0.f, 0.f};
  int cnt0 = 0, cnt1 = 0, cnt2 = 0;

  // prologue: prefetch step 0
  float4 ld[4];
  int labv;
  {
    const float4* src = (const float4*)(emb + base * DIM);
#pragma unroll
    for (int r = 0; r < 4; ++r) ld[r] = src[lane + 64 * r];
    labv = lab[base + (lane & 31)];
  }

  for (int step = 0; step < STEPS; ++step) {
#pragma unroll
    for (int r = 0; r < 4; ++r) {
      const int i = lane + 64 * r;
      const int p = i >> 3, d0 = (i & 7) * 4;
      st[(d0 + 0) * 33 + p] = ld[r].x;
      st[(d0 + 1) * 33 + p] = ld[r].y;
      st[(d0 + 2) * 33 + p] = ld[r].z;
      st[(d0 + 3) * 33 + p] = ld[r].w;
    }
    const int labv_c = labv;

    if (step < STEPS - 1) {
      const float4* src = (const float4*)(emb + (base + (step + 1) * 32) * DIM);
#pragma unroll
      for (int r = 0; r < 4; ++r) ld[r] = src[lane + 64 * r];
      labv = lab[base + (step + 1) * 32 + (lane & 31)];
    }

    bf16x8 a0, a1, a2;
#pragma unroll
    for (int j = 0; j < 8; ++j) {
      const int lj = __shfl(labv_c, g * 8 + j);
      const int h0 = (lj == m0), h1 = (lj == m0 + 16), h2 = (lj == m0 + 32);
      a0[j] = h0 ? (short)0x3F80 : (short)0;
      a1[j] = h1 ? (short)0x3F80 : (short)0;
      a2[j] = h2 ? (short)0x3F80 : (short)0;
      cnt0 += h0; cnt1 += h1; cnt2 += h2;
    }

    bf16x8 b0, b1;
#pragma unroll
    for (int j = 0; j < 8; ++j) {
      b0[j] = f2bf(st[m0 * 33 + g * 8 + j]);
      b1[j] = f2bf(st[(m0 + 16) * 33 + g * 8 + j]);
    }

    acc[0][0] = __builtin_amdgcn_mfma_f32_16x16x32_bf16(a0, b0, acc[0][0], 0, 0, 0);
    acc[0][1] = __builtin_amdgcn_mfma_f32_16x16x32_bf16(a0, b1, acc[0][1], 0, 0, 0);
    acc[1][0] = __builtin_amdgcn_mfma_f32_16x16x32_bf16(a1, b0, acc[1][0], 0, 0, 0);
    acc[1][1] = __builtin_amdgcn_mfma_f32_16x16x32_bf16(a1, b1, acc[1][1], 0, 0, 0);
    acc[2][0] = __builtin_amdgcn_mfma_f32_16x16x32_bf16(a2, b0, acc[2][0], 0, 0, 0);
    acc[2][1] = __builtin_amdgcn_mfma_f32_16x16x32_bf16(a2, b1, acc[2][1], 0, 0, 0);
  }

  cnt0 += __shfl_xor(cnt0, 16); cnt0 += __shfl_xor(cnt0, 32);
  cnt1 += __shfl_xor(cnt1, 16); cnt1 += __shfl_xor(cnt1, 32);
  cnt2 += __shfl_xor(cnt2, 16); cnt2 += __shfl_xor(cnt2, 32);
  if (lane < 16)            s_cnt4[w][m0]      = cnt0;
  else if (lane < 32)       s_cnt4[w][m0 + 16] = cnt1;
  if (lane == 32)           s_cnt4[w][32]      = cnt2;

#pragma unroll
  for (int t = 0; t < 2; ++t)
#pragma unroll
    for (int u = 0; u < 2; ++u)
#pragma unroll
      for (int r = 0; r < 4; ++r)
        st[(t * 16 + g * 4 + r) * DIM + m0 + 16 * u] = acc[t][u][r];
  if (lane < 16) {
    st[32 * DIM + m0]      = acc[2][0][0];
    st[32 * DIM + m0 + 16] = acc[2][1][0];
  }
  __syncthreads();

  // cross-wave reduce + PLAIN coalesced partial stores (no atomics)
  const size_t pb = (size_t)b * G1X + blockIdx.x;
  for (int i = tid; i < NLAB * DIM; i += 256) {
    const float v = s_stage[0][i] + s_stage[1][i] + s_stage[2][i] + s_stage[3][i];
    psum[pb * (NLAB * DIM) + i] = v;
  }
  if (tid < NLAB) {
    const int c = s_cnt4[0][tid] + s_cnt4[1][tid] + s_cnt4[2][tid] + s_cnt4[3][tid];
    pcnt[pb * NLAB + tid] = (float)c;
  }
}

// R10: folds the per-block partials into gsum/gcnt. 8-way sliced over
// blockIdx.y (each slice sums G1X/8=32 partials, coalesced reads, then one
// atomicAdd -> only 8 atomics per output address).
__global__ __launch_bounds__(256) void reduce_kernel(
    const float* __restrict__ psum, const float* __restrict__ pcnt,
    float* __restrict__ gsum, float* __restrict__ gcnt) {
  constexpr int TOT = BATCH * NLAB * DIM;   // 8448
  constexpr int KS  = G1X / 8;              // 32 partials per slice
  const int slice = blockIdx.y;
  const int o = blockIdx.x * 256 + threadIdx.x;
  if (o < TOT) {
    const int b = o / (NLAB * DIM), i = o - b * (NLAB * DIM);
    const float* src = psum + ((size_t)b * G1X + slice * KS) * (NLAB * DIM) + i;
    float a0 = 0.f, a1 = 0.f, a2 = 0.f, a3 = 0.f;
#pragma unroll
    for (int k = 0; k < KS; k += 4) {
      a0 += src[(size_t)(k + 0) * (NLAB * DIM)];
      a1 += src[(size_t)(k + 1) * (NLAB * DIM)];
      a2 += src[(size_t)(k + 2) * (NLAB * DIM)];
      a3 += src[(size_t)(k + 3) * (NLAB * DIM)];
    }
    atomicAdd(&gsum[o], (a0 + a1) + (a2 + a3));
  } else if (o - TOT < BATCH * NLAB) {
    const int o2 = o - TOT;
    const int b = o2 / NLAB, l = o2 - b * NLAB;
    const float* src = pcnt + ((size_t)b * G1X + slice * KS) * NLAB + l;
    float a = 0.f;
#pragma unroll
    for (int k = 0; k < KS; ++k) a += src[(size_t)k * NLAB];
    atomicAdd(&gcnt[o2], a);
  }
}

// Pass 2: per-point hinge, streaming pipeline, NO ATOMICS. (unchanged R9)
#define CN 8                       // points per chunk
#define P2_ISSUE(LB, EB, C)                                                   \
  {                                                                           \
    _Pragma("unroll")                                                         \
    for (int j = 0; j < CN; ++j) {                                            \
      const size_t it = (size_t)(C) * CN + j;                                 \
      const unsigned long long al =                                           \
          (unsigned long long)(lab + base + p0 + it * PSTRIDE);               \
      asm volatile("global_load_dword %0, %1, off" : "=&v"(LB[j]) : "v"(al)); \
    }                                                                         \
    _Pragma("unroll")                                                         \
    for (int j = 0; j < CN; ++j) {                                            \
      const size_t it = (size_t)(C) * CN + j;                                 \
      const unsigned long long ae =                                           \
          (unsigned long long)(emb + (base + p0 + it * PSTRIDE) * DIM + d0);  \
      asm volatile("global_load_dwordx4 %0, %1, off" : "=&v"(EB[j]) : "v"(ae)); \
    }                                                                         \
  }

#define P2_COMPUTE(LB, EB)                                                    \
  {                                                                           \
    float s[CN];                                                              \
    _Pragma("unroll")                                                         \
    for (int j = 0; j < CN; ++j) {                                            \
      const f32x4 mv = *(const f32x4*)(s_mean + LB[j] * 36 + d0);             \
      const float dx = EB[j][0] - mv[0], dy = EB[j][1] - mv[1];               \
      const float dz = EB[j][2] - mv[2], dw = EB[j][3] - mv[3];               \
      s[j] = dx * dx + dy * dy + dz * dz + dw * dw;                           \
    }                                                                         \
    _Pragma("unroll")                                                         \
    for (int j = 0; j < CN; ++j) {                                            \
      s[j] += __shfl_xor(s[j], 1);                                            \
      s[j] += __shfl_xor(s[j], 2);                                            \
      s[j] += __shfl_xor(s[j], 4);                                            \
    }                                                                         \
    float sv = s[0];                                                          \
    int   lv = LB[0];                                                         \
    _Pragma("unroll")                                                         \
    for (int j = 1; j < CN; ++j) {                                            \
      sv = (lane8 == j) ? s[j] : sv;                                          \
      lv = (lane8 == j) ? LB[j] : lv;                                         \
    }                                                                         \
    const float dist = sqrtf(sv + 1e-24f);                                    \
    wacc += s_w[lv] * fmaxf(dist - 0.1f, 0.f);                                \
  }

__global__ __launch_bounds__(256, 4) void pass2_kernel(
    const float* __restrict__ emb, const int* __restrict__ lab,
    const float* __restrict__ gsum, const float* __restrict__ gcnt,
    float* __restrict__ pull_part) {
  const int b   = blockIdx.y;
  const int tid = threadIdx.x;
  __shared__ __align__(16) float s_mean[NLAB * 36];
  __shared__ float s_w[NLAB];
  __shared__ float s_red[4];

  for (int i = tid; i < NLAB * DIM; i += 256) {
    const int l = i >> 5, d = i & 31;
    const float c = gcnt[b * NLAB + l];
    s_mean[l * 36 + d] = gsum[b * (NLAB * DIM) + i] / fmaxf(c, 1.0f);
  }
  if (tid < 64) {
    const float c = (tid < NLAB) ? gcnt[b * NLAB + tid] : 0.f;
    const int pres = (tid >= 1 && tid < NLAB && c > 0.f) ? 1 : 0;
    const unsigned long long bal = __ballot(pres);
    const float n_inst = (float)__popcll(bal);
    if (tid < NLAB)
      s_w[tid] = pres ? 1.f / (fmaxf(c, 1.f) * (n_inst + 1e-6f)) : 0.f;
  }
  __syncthreads();   // drains vmcnt to 0: counted waits below are exact

  const int sub   = tid >> 3;
  const int lane8 = tid & 7;
  const int d0    = lane8 << 2;
  const size_t base = (size_t)b * NPTS;
  const int p0 = blockIdx.x * 32 + sub;
  constexpr int PSTRIDE = BPB2 * 32;            // 4096
  constexpr int NIT     = NPTS / PSTRIDE;       // 32 iterations / thread
  constexpr int NCH     = NIT / CN;             // 4 chunks

  int   labsA[CN], labsB[CN];
  f32x4 eA[CN], eB[CN];
  float wacc = 0.f;

  P2_ISSUE(labsA, eA, 0);
#pragma unroll
  for (int cc = 0; cc < NCH; cc += 2) {
    if (cc + 1 < NCH) P2_ISSUE(labsB, eB, cc + 1);
    if (cc + 1 < NCH) { asm volatile("s_waitcnt vmcnt(16)" ::: "memory"); }
    else              { asm volatile("s_waitcnt vmcnt(0)"  ::: "memory"); }
    __builtin_amdgcn_sched_barrier(0);
    P2_COMPUTE(labsA, eA);
    if (cc + 1 < NCH) {
      if (cc + 2 < NCH) P2_ISSUE(labsA, eA, cc + 2);
      if (cc + 2 < NCH) { asm volatile("s_waitcnt vmcnt(16)" ::: "memory"); }
      else              { asm volatile("s_waitcnt vmcnt(0)"  ::: "memory"); }
      __builtin_amdgcn_sched_barrier(0);
      P2_COMPUTE(labsB, eB);
    }
  }

#pragma unroll
  for (int mm = 1; mm < 64; mm <<= 1) wacc += __shfl_xor(wacc, mm);
  if ((tid & 63) == 0) s_red[tid >> 6] = wacc;
  __syncthreads();
  if (tid == 0)
    pull_part[b * BPB2 + blockIdx.x] =
        s_red[0] + s_red[1] + s_red[2] + s_red[3];
}

// Per-batch push + final combine. One wave per batch, single block.
__global__ __launch_bounds__(512) void finish_kernel(
    const float* __restrict__ gsum, const float* __restrict__ gcnt,
    const float* __restrict__ pull_part, float* __restrict__ out) {
  const int tid = threadIdx.x;
  const int b   = tid >> 6;
  const int t   = tid & 63;
  __shared__ __align__(16) float s_mn[BATCH * 32 * DIM];
  __shared__ float s_ps[BATCH];
  __shared__ float s_pl[BATCH];
  float* mn = s_mn + b * 32 * DIM;

  // pull: wave b reduces its BPB2(=128) block partials
  {
    float plsum = pull_part[b * BPB2 + t] + pull_part[b * BPB2 + 64 + t];
#pragma unroll
    for (int m = 1; m < 64; m <<= 1) plsum += __shfl_xor(plsum, m);
    if (t == 0) s_pl[b] = plsum;
  }

  int pres = 0;
  if (t < 32) {
    const int l = t + 1;
    const float cnt = gcnt[b * NLAB + l];
    pres = (cnt > 0.f) ? 1 : 0;
    const float inv = 1.f / fmaxf(cnt, 1.f);
    float v[DIM];
    float n2 = 0.f;
    for (int d = 0; d < DIM; d++) {
      v[d] = gsum[b * (NLAB * DIM) + l * DIM + d] * inv;
      n2  += v[d] * v[d];
    }
    const float scale = 1.f / fmaxf(sqrtf(n2), 1e-12f);
    for (int d = 0; d < DIM; d++) mn[t * DIM + d] = v[d] * scale;
  }
  const unsigned long long bal = __ballot(pres);
  const unsigned int pmask32 = (unsigned int)(bal & 0xFFFFFFFFull);
  const int n_inst = __popc(pmask32);

  __syncthreads();

  float hp_sum = 0.f, pm_sum = 0.f;
  for (int idx = t; idx < 1024; idx += 64) {
    const int i = idx >> 5, j = idx & 31;
    if (j > i && ((pmask32 >> i) & 1u) && ((pmask32 >> j) & 1u)) {
      const float4* a = (const float4*)(mn + i * DIM);
      const float4* c = (const float4*)(mn + j * DIM);
      float sq = 0.f;
      for (int q = 0; q < 8; q++) {
        const float4 av = a[q], cv = c[q];
        const float dx = av.x - cv.x, dy = av.y - cv.y;
        const float dz = av.z - cv.z, dw = av.w - cv.w;
        sq += dx * dx + dy * dy + dz * dz + dw * dw;
      }
      const float dmat = sqrtf(sq + 1e-24f);
      hp_sum += fmaxf(1.0f - dmat, 0.f);   // 2*DELTA_D = 1.0
      pm_sum += 1.f;
    }
  }
  for (int m = 1; m < 64; m <<= 1) {
    hp_sum += __shfl_xor(hp_sum, m);
    pm_sum += __shfl_xor(pm_sum, m);
  }
  const float push = (n_inst > 1) ? hp_sum / (pm_sum + 1e-6f) : 0.f;
  if (t == 0) s_ps[b] = push;
  __syncthreads();

  if (tid < 64) {
    float pl = (t < BATCH) ? s_pl[t] : 0.f;
    float ps = (t < BATCH) ? s_ps[t] : 0.f;
#pragma unroll
    for (int m = 1; m < 64; m <<= 1) {
      pl += __shfl_xor(pl, m);
      ps += __shfl_xor(ps, m);
    }
    if (t == 0) {
      const float pull_m = pl / (float)BATCH;
      const float push_m = ps / (float)BATCH;
      out[0] = pull_m + push_m;
      out[1] = pull_m;
      out[2] = push_m;
    }
  }
}

extern "C" void kernel_launch(void* const* d_in, const int* in_sizes, int n_in,
                              void* d_out, int out_size, void* d_ws, size_t ws_size,
                              hipStream_t stream) {
  const float* emb = (const float*)d_in[0];
  const int*   lab = (const int*)d_in[1];
  float* out = (float*)d_out;
  float* ws  = (float*)d_ws;

  float* gcnt  = ws + OFF_CNT;
  float* gsum  = ws + OFF_SUM;
  float* pullp = ws + OFF_PULL;
  float* psum  = ws + OFF_PSUM;
  float* pcnt  = ws + OFF_PCNT;

  // only gsum/gcnt need zeroing (reduce_kernel accumulates into them)
  hipMemsetAsync(d_ws, 0, (OFF_SUM + BATCH * NLAB * DIM) * sizeof(float), stream);

  dim3 grid1(G1X, BATCH);
  dim3 gridR((BATCH * NLAB * DIM + BATCH * NLAB + 255) / 256, 8);
  dim3 grid2(BPB2, BATCH);
  pass1_kernel<<<grid1, 256, 0, stream>>>(emb, lab, psum, pcnt);
  reduce_kernel<<<gridR, 256, 0, stream>>>(psum, pcnt, gsum, gcnt);
  pass2_kernel<<<grid2, 256, 0, stream>>>(emb, lab, gsum, gcnt, pullp);
  finish_kernel<<<1, 512, 0, stream>>>(gsum, gcnt, pullp, out);
}

// Round 7
// 234.750 us; speedup vs baseline: 1.3072x; 1.0102x over previous
//
#include <hip/hip_runtime.h>
#include <hip/hip_bf16.h>

#define BATCH 8
#define NPTS  131072
#define DIM   32
#define NLAB  33
#define G1X   128             // pass1 blocks per batch -> 1024 blocks, 8 tiles/wave
#define P1PTS 1024            // points per pass1 block (256 per wave)
#define BPB2  128             // pass2 blocks per batch

// ws float layout
#define OFF_CNT   0                                   // gcnt: BATCH*NLAB = 264
#define OFF_SUM   264                                 // gsum: BATCH*NLAB*DIM = 8448
#define OFF_PULL  (264 + 8448)                        // pull partials: BATCH*BPB2 = 1024
#define OFF_PSUM  (OFF_PULL + BATCH * BPB2)           // pass1 sum partials: 8*128*1056
#define OFF_PCNT  (OFF_PSUM + BATCH * G1X * NLAB * DIM)  // pass1 cnt partials: 8*128*33
#define WS_FLOATS (OFF_PCNT + BATCH * G1X * NLAB)

typedef short  bf16x8 __attribute__((ext_vector_type(8)));
typedef float  f32x4  __attribute__((ext_vector_type(4)));

static __device__ __forceinline__ short f2bf(float f) {
  __hip_bfloat16 h = __float2bfloat16(f);
  return *reinterpret_cast<short*>(&h);
}

// Pass 1: sums[l][d] = onehot(labels)^T @ E via MFMA one-hot GEMM.
// R11 post-mortem of R10: atomic removal gained ~0 -> the stall was never
// the epilogue; R4 counters (all pipes idle THROUGHOUT, 1.31M bank
// conflicts, ~47K cyc per 32-pt step) indict the hot-loop serial chain
// global->LDS-stage->lgkmcnt->LDS-read->cvt->MFMA. This version: NO LDS
// in the hot loop. The B-fragment transpose is done by the load pattern
// itself: lane(n,g) loads E[g*8+j][n(+16)] directly via 16 dword loads
// off one voffset with literal offset: immediates (still 64B-coalesced
// per 16-lane group). Streaming asm-volatile pipeline with counted
// vmcnt(17), 2 tiles deep — the pattern that fixed pass2.
#define P1_ISSUE(LABD, BV, T)                                                 \
  {                                                                           \
    const int vt = vbase + (T) * 4096;                                        \
    const int vl = lloff + (T) * 128;                                         \
    asm volatile("global_load_dword %0, %1, %2"                               \
                 : "=&v"(LABD) : "v"(vl), "s"(lbase));                        \
    asm volatile("global_load_dword %0, %1, %2"            : "=&v"(BV[0])  : "v"(vt), "s"(ebase)); \
    asm volatile("global_load_dword %0, %1, %2 offset:128" : "=&v"(BV[1])  : "v"(vt), "s"(ebase)); \
    asm volatile("global_load_dword %0, %1, %2 offset:256" : "=&v"(BV[2])  : "v"(vt), "s"(ebase)); \
    asm volatile("global_load_dword %0, %1, %2 offset:384" : "=&v"(BV[3])  : "v"(vt), "s"(ebase)); \
    asm volatile("global_load_dword %0, %1, %2 offset:512" : "=&v"(BV[4])  : "v"(vt), "s"(ebase)); \
    asm volatile("global_load_dword %0, %1, %2 offset:640" : "=&v"(BV[5])  : "v"(vt), "s"(ebase)); \
    asm volatile("global_load_dword %0, %1, %2 offset:768" : "=&v"(BV[6])  : "v"(vt), "s"(ebase)); \
    asm volatile("global_load_dword %0, %1, %2 offset:896" : "=&v"(BV[7])  : "v"(vt), "s"(ebase)); \
    asm volatile("global_load_dword %0, %1, %2 offset:64"  : "=&v"(BV[8])  : "v"(vt), "s"(ebase)); \
    asm volatile("global_load_dword %0, %1, %2 offset:192" : "=&v"(BV[9])  : "v"(vt), "s"(ebase)); \
    asm volatile("global_load_dword %0, %1, %2 offset:320" : "=&v"(BV[10]) : "v"(vt), "s"(ebase)); \
    asm volatile("global_load_dword %0, %1, %2 offset:448" : "=&v"(BV[11]) : "v"(vt), "s"(ebase)); \
    asm volatile("global_load_dword %0, %1, %2 offset:576" : "=&v"(BV[12]) : "v"(vt), "s"(ebase)); \
    asm volatile("global_load_dword %0, %1, %2 offset:704" : "=&v"(BV[13]) : "v"(vt), "s"(ebase)); \
    asm volatile("global_load_dword %0, %1, %2 offset:832" : "=&v"(BV[14]) : "v"(vt), "s"(ebase)); \
    asm volatile("global_load_dword %0, %1, %2 offset:960" : "=&v"(BV[15]) : "v"(vt), "s"(ebase)); \
  }

#define P1_COMPUTE(LABD, BV)                                                  \
  {                                                                           \
    const int labv_c = LABD;                                                  \
    bf16x8 a0, a1, a2, b0, b1;                                                \
    _Pragma("unroll")                                                         \
    for (int j = 0; j < 8; ++j) {                                             \
      const int lj = __shfl(labv_c, g * 8 + j);                               \
      const int h0 = (lj == m0), h1 = (lj == m0 + 16), h2 = (lj == m0 + 32);  \
      a0[j] = h0 ? (short)0x3F80 : (short)0;                                  \
      a1[j] = h1 ? (short)0x3F80 : (short)0;                                  \
      a2[j] = h2 ? (short)0x3F80 : (short)0;                                  \
      cnt0 += h0; cnt1 += h1; cnt2 += h2;                                     \
      b0[j] = f2bf(BV[j]);                                                    \
      b1[j] = f2bf(BV[8 + j]);                                                \
    }                                                                         \
    acc[0][0] = __builtin_amdgcn_mfma_f32_16x16x32_bf16(a0, b0, acc[0][0], 0, 0, 0); \
    acc[0][1] = __builtin_amdgcn_mfma_f32_16x16x32_bf16(a0, b1, acc[0][1], 0, 0, 0); \
    acc[1][0] = __builtin_amdgcn_mfma_f32_16x16x32_bf16(a1, b0, acc[1][0], 0, 0, 0); \
    acc[1][1] = __builtin_amdgcn_mfma_f32_16x16x32_bf16(a1, b1, acc[1][1], 0, 0, 0); \
    acc[2][0] = __builtin_amdgcn_mfma_f32_16x16x32_bf16(a2, b0, acc[2][0], 0, 0, 0); \
    acc[2][1] = __builtin_amdgcn_mfma_f32_16x16x32_bf16(a2, b1, acc[2][1], 0, 0, 0); \
  }

__global__ __launch_bounds__(256) void pass1_kernel(
    const float* __restrict__ emb, const int* __restrict__ lab,
    float* __restrict__ psum, float* __restrict__ pcnt) {
  const int b    = blockIdx.y;
  const int tid  = threadIdx.x;
  const int w    = __builtin_amdgcn_readfirstlane(tid >> 6);   // wave-uniform
  const int lane = tid & 63;
  const int m0   = lane & 15;      // A row (label in tile) / B col (dim)
  const int g    = lane >> 4;      // k-group

  // LDS only for the one-shot epilogue reduce (not in the hot loop)
  __shared__ float s_stage[4][NLAB * DIM];   // 16.9 KB
  __shared__ int   s_cnt4[4][NLAB];

  const size_t base = (size_t)b * NPTS + (size_t)blockIdx.x * P1PTS
                    + (size_t)w * 256;
  const float* ebase = emb + base * DIM;
  const int*   lbase = lab + base;
  const int vbase = g * 1024 + m0 * 4;   // byte off: point g*8 (+j via imm), dim m0 (+16u via imm)
  const int lloff = (lane & 31) * 4;

  f32x4 acc[3][2];
#pragma unroll
  for (int t = 0; t < 3; ++t)
#pragma unroll
    for (int u = 0; u < 2; ++u) acc[t][u] = (f32x4){0.f, 0.f, 0.f, 0.f};
  int cnt0 = 0, cnt1 = 0, cnt2 = 0;

  int   labA, labB;
  float bvA[16], bvB[16];

  P1_ISSUE(labA, bvA, 0);
#pragma unroll
  for (int t = 0; t < 8; t += 2) {
    P1_ISSUE(labB, bvB, t + 1);
    asm volatile("s_waitcnt vmcnt(17)" ::: "memory");
    __builtin_amdgcn_sched_barrier(0);
    P1_COMPUTE(labA, bvA);
    if (t + 2 < 8) {
      P1_ISSUE(labA, bvA, t + 2);
      asm volatile("s_waitcnt vmcnt(17)" ::: "memory");
    } else {
      asm volatile("s_waitcnt vmcnt(0)" ::: "memory");
    }
    __builtin_amdgcn_sched_barrier(0);
    P1_COMPUTE(labB, bvB);
  }

  // counts: reduce across the 4 k-groups (lanes l, l+16, l+32, l+48)
  cnt0 += __shfl_xor(cnt0, 16); cnt0 += __shfl_xor(cnt0, 32);
  cnt1 += __shfl_xor(cnt1, 16); cnt1 += __shfl_xor(cnt1, 32);
  cnt2 += __shfl_xor(cnt2, 16); cnt2 += __shfl_xor(cnt2, 32);
  if (lane < 16)            s_cnt4[w][m0]      = cnt0;
  else if (lane < 32)       s_cnt4[w][m0 + 16] = cnt1;
  if (lane == 32)           s_cnt4[w][32]      = cnt2;

  // dump accumulators as [label][dim]; D row(label) = g*4+r, col = m0(+16u)
  float* st = s_stage[w];
#pragma unroll
  for (int t = 0; t < 2; ++t)
#pragma unroll
    for (int u = 0; u < 2; ++u)
#pragma unroll
      for (int r = 0; r < 4; ++r)
        st[(t * 16 + g * 4 + r) * DIM + m0 + 16 * u] = acc[t][u][r];
  if (lane < 16) {
    st[32 * DIM + m0]      = acc[2][0][0];
    st[32 * DIM + m0 + 16] = acc[2][1][0];
  }
  __syncthreads();

  // cross-wave reduce + PLAIN coalesced partial stores (no atomics)
  const size_t pb = (size_t)b * G1X + blockIdx.x;
  for (int i = tid; i < NLAB * DIM; i += 256) {
    const float v = s_stage[0][i] + s_stage[1][i] + s_stage[2][i] + s_stage[3][i];
    psum[pb * (NLAB * DIM) + i] = v;
  }
  if (tid < NLAB) {
    const int c = s_cnt4[0][tid] + s_cnt4[1][tid] + s_cnt4[2][tid] + s_cnt4[3][tid];
    pcnt[pb * NLAB + tid] = (float)c;
  }
}

// Folds per-block partials into gsum/gcnt. 8-way sliced over blockIdx.y
// (each slice sums G1X/8=16 partials, coalesced; 8 atomics per address).
__global__ __launch_bounds__(256) void reduce_kernel(
    const float* __restrict__ psum, const float* __restrict__ pcnt,
    float* __restrict__ gsum, float* __restrict__ gcnt) {
  constexpr int TOT = BATCH * NLAB * DIM;   // 8448
  constexpr int KS  = G1X / 8;              // 16 partials per slice
  const int slice = blockIdx.y;
  const int o = blockIdx.x * 256 + threadIdx.x;
  if (o < TOT) {
    const int b = o / (NLAB * DIM), i = o - b * (NLAB * DIM);
    const float* src = psum + ((size_t)b * G1X + slice * KS) * (NLAB * DIM) + i;
    float a0 = 0.f, a1 = 0.f, a2 = 0.f, a3 = 0.f;
#pragma unroll
    for (int k = 0; k < KS; k += 4) {
      a0 += src[(size_t)(k + 0) * (NLAB * DIM)];
      a1 += src[(size_t)(k + 1) * (NLAB * DIM)];
      a2 += src[(size_t)(k + 2) * (NLAB * DIM)];
      a3 += src[(size_t)(k + 3) * (NLAB * DIM)];
    }
    atomicAdd(&gsum[o], (a0 + a1) + (a2 + a3));
  } else if (o - TOT < BATCH * NLAB) {
    const int o2 = o - TOT;
    const int b = o2 / NLAB, l = o2 - b * NLAB;
    const float* src = pcnt + ((size_t)b * G1X + slice * KS) * NLAB + l;
    float a = 0.f;
#pragma unroll
    for (int k = 0; k < KS; ++k) a += src[(size_t)k * NLAB];
    atomicAdd(&gcnt[o2], a);
  }
}

// Pass 2: per-point hinge, streaming pipeline, NO ATOMICS. (unchanged R9)
#define CN 8                       // points per chunk
#define P2_ISSUE(LB, EB, C)                                                   \
  {                                                                           \
    _Pragma("unroll")                                                         \
    for (int j = 0; j < CN; ++j) {                                            \
      const size_t it = (size_t)(C) * CN + j;                                 \
      const unsigned long long al =                                           \
          (unsigned long long)(lab + base + p0 + it * PSTRIDE);               \
      asm volatile("global_load_dword %0, %1, off" : "=&v"(LB[j]) : "v"(al)); \
    }                                                                         \
    _Pragma("unroll")                                                         \
    for (int j = 0; j < CN; ++j) {                                            \
      const size_t it = (size_t)(C) * CN + j;                                 \
      const unsigned long long ae =                                           \
          (unsigned long long)(emb + (base + p0 + it * PSTRIDE) * DIM + d0);  \
      asm volatile("global_load_dwordx4 %0, %1, off" : "=&v"(EB[j]) : "v"(ae)); \
    }                                                                         \
  }

#define P2_COMPUTE(LB, EB)                                                    \
  {                                                                           \
    float s[CN];                                                              \
    _Pragma("unroll")                                                         \
    for (int j = 0; j < CN; ++j) {                                            \
      const f32x4 mv = *(const f32x4*)(s_mean + LB[j] * 36 + d0);             \
      const float dx = EB[j][0] - mv[0], dy = EB[j][1] - mv[1];               \
      const float dz = EB[j][2] - mv[2], dw = EB[j][3] - mv[3];               \
      s[j] = dx * dx + dy * dy + dz * dz + dw * dw;                           \
    }                                                                         \
    _Pragma("unroll")                                                         \
    for (int j = 0; j < CN; ++j) {                                            \
      s[j] += __shfl_xor(s[j], 1);                                            \
      s[j] += __shfl_xor(s[j], 2);                                            \
      s[j] += __shfl_xor(s[j], 4);                                            \
    }                                                                         \
    float sv = s[0];                                                          \
    int   lv = LB[0];                                                         \
    _Pragma("unroll")                                                         \
    for (int j = 1; j < CN; ++j) {                                            \
      sv = (lane8 == j) ? s[j] : sv;                                          \
      lv = (lane8 == j) ? LB[j] : lv;                                         \
    }                                                                         \
    const float dist = sqrtf(sv + 1e-24f);                                    \
    wacc += s_w[lv] * fmaxf(dist - 0.1f, 0.f);                                \
  }

__global__ __launch_bounds__(256, 4) void pass2_kernel(
    const float* __restrict__ emb, const int* __restrict__ lab,
    const float* __restrict__ gsum, const float* __restrict__ gcnt,
    float* __restrict__ pull_part) {
  const int b   = blockIdx.y;
  const int tid = threadIdx.x;
  __shared__ __align__(16) float s_mean[NLAB * 36];
  __shared__ float s_w[NLAB];
  __shared__ float s_red[4];

  for (int i = tid; i < NLAB * DIM; i += 256) {
    const int l = i >> 5, d = i & 31;
    const float c = gcnt[b * NLAB + l];
    s_mean[l * 36 + d] = gsum[b * (NLAB * DIM) + i] / fmaxf(c, 1.0f);
  }
  if (tid < 64) {
    const float c = (tid < NLAB) ? gcnt[b * NLAB + tid] : 0.f;
    const int pres = (tid >= 1 && tid < NLAB && c > 0.f) ? 1 : 0;
    const unsigned long long bal = __ballot(pres);
    const float n_inst = (float)__popcll(bal);
    if (tid < NLAB)
      s_w[tid] = pres ? 1.f / (fmaxf(c, 1.f) * (n_inst + 1e-6f)) : 0.f;
  }
  __syncthreads();   // drains vmcnt to 0: counted waits below are exact

  const int sub   = tid >> 3;
  const int lane8 = tid & 7;
  const int d0    = lane8 << 2;
  const size_t base = (size_t)b * NPTS;
  const int p0 = blockIdx.x * 32 + sub;
  constexpr int PSTRIDE = BPB2 * 32;            // 4096
  constexpr int NIT     = NPTS / PSTRIDE;       // 32 iterations / thread
  constexpr int NCH     = NIT / CN;             // 4 chunks

  int   labsA[CN], labsB[CN];
  f32x4 eA[CN], eB[CN];
  float wacc = 0.f;

  P2_ISSUE(labsA, eA, 0);
#pragma unroll
  for (int cc = 0; cc < NCH; cc += 2) {
    if (cc + 1 < NCH) P2_ISSUE(labsB, eB, cc + 1);
    if (cc + 1 < NCH) { asm volatile("s_waitcnt vmcnt(16)" ::: "memory"); }
    else              { asm volatile("s_waitcnt vmcnt(0)"  ::: "memory"); }
    __builtin_amdgcn_sched_barrier(0);
    P2_COMPUTE(labsA, eA);
    if (cc + 1 < NCH) {
      if (cc + 2 < NCH) P2_ISSUE(labsA, eA, cc + 2);
      if (cc + 2 < NCH) { asm volatile("s_waitcnt vmcnt(16)" ::: "memory"); }
      else              { asm volatile("s_waitcnt vmcnt(0)"  ::: "memory"); }
      __builtin_amdgcn_sched_barrier(0);
      P2_COMPUTE(labsB, eB);
    }
  }

#pragma unroll
  for (int mm = 1; mm < 64; mm <<= 1) wacc += __shfl_xor(wacc, mm);
  if ((tid & 63) == 0) s_red[tid >> 6] = wacc;
  __syncthreads();
  if (tid == 0)
    pull_part[b * BPB2 + blockIdx.x] =
        s_red[0] + s_red[1] + s_red[2] + s_red[3];
}

// Per-batch push + final combine. One wave per batch, single block.
__global__ __launch_bounds__(512) void finish_kernel(
    const float* __restrict__ gsum, const float* __restrict__ gcnt,
    const float* __restrict__ pull_part, float* __restrict__ out) {
  const int tid = threadIdx.x;
  const int b   = tid >> 6;
  const int t   = tid & 63;
  __shared__ __align__(16) float s_mn[BATCH * 32 * DIM];
  __shared__ float s_ps[BATCH];
  __shared__ float s_pl[BATCH];
  float* mn = s_mn + b * 32 * DIM;

  // pull: wave b reduces its BPB2(=128) block partials
  {
    float plsum = pull_part[b * BPB2 + t] + pull_part[b * BPB2 + 64 + t];
#pragma unroll
    for (int m = 1; m < 64; m <<= 1) plsum += __shfl_xor(plsum, m);
    if (t == 0) s_pl[b] = plsum;
  }

  int pres = 0;
  if (t < 32) {
    const int l = t + 1;
    const float cnt = gcnt[b * NLAB + l];
    pres = (cnt > 0.f) ? 1 : 0;
    const float inv = 1.f / fmaxf(cnt, 1.f);
    float v[DIM];
    float n2 = 0.f;
    for (int d = 0; d < DIM; d++) {
      v[d] = gsum[b * (NLAB * DIM) + l * DIM + d] * inv;
      n2  += v[d] * v[d];
    }
    const float scale = 1.f / fmaxf(sqrtf(n2), 1e-12f);
    for (int d = 0; d < DIM; d++) mn[t * DIM + d] = v[d] * scale;
  }
  const unsigned long long bal = __ballot(pres);
  const unsigned int pmask32 = (unsigned int)(bal & 0xFFFFFFFFull);
  const int n_inst = __popc(pmask32);

  __syncthreads();

  float hp_sum = 0.f, pm_sum = 0.f;
  for (int idx = t; idx < 1024; idx += 64) {
    const int i = idx >> 5, j = idx & 31;
    if (j > i && ((pmask32 >> i) & 1u) && ((pmask32 >> j) & 1u)) {
      const float4* a = (const float4*)(mn + i * DIM);
      const float4* c = (const float4*)(mn + j * DIM);
      float sq = 0.f;
      for (int q = 0; q < 8; q++) {
        const float4 av = a[q], cv = c[q];
        const float dx = av.x - cv.x, dy = av.y - cv.y;
        const float dz = av.z - cv.z, dw = av.w - cv.w;
        sq += dx * dx + dy * dy + dz * dz + dw * dw;
      }
      const float dmat = sqrtf(sq + 1e-24f);
      hp_sum += fmaxf(1.0f - dmat, 0.f);   // 2*DELTA_D = 1.0
      pm_sum += 1.f;
    }
  }
  for (int m = 1; m < 64; m <<= 1) {
    hp_sum += __shfl_xor(hp_sum, m);
    pm_sum += __shfl_xor(pm_sum, m);
  }
  const float push = (n_inst > 1) ? hp_sum / (pm_sum + 1e-6f) : 0.f;
  if (t == 0) s_ps[b] = push;
  __syncthreads();

  if (tid < 64) {
    float pl = (t < BATCH) ? s_pl[t] : 0.f;
    float ps = (t < BATCH) ? s_ps[t] : 0.f;
#pragma unroll
    for (int m = 1; m < 64; m <<= 1) {
      pl += __shfl_xor(pl, m);
      ps += __shfl_xor(ps, m);
    }
    if (t == 0) {
      const float pull_m = pl / (float)BATCH;
      const float push_m = ps / (float)BATCH;
      out[0] = pull_m + push_m;
      out[1] = pull_m;
      out[2] = push_m;
    }
  }
}

extern "C" void kernel_launch(void* const* d_in, const int* in_sizes, int n_in,
                              void* d_out, int out_size, void* d_ws, size_t ws_size,
                              hipStream_t stream) {
  const float* emb = (const float*)d_in[0];
  const int*   lab = (const int*)d_in[1];
  float* out = (float*)d_out;
  float* ws  = (float*)d_ws;

  float* gcnt  = ws + OFF_CNT;
  float* gsum  = ws + OFF_SUM;
  float* pullp = ws + OFF_PULL;
  float* psum  = ws + OFF_PSUM;
  float* pcnt  = ws + OFF_PCNT;

  // only gsum/gcnt need zeroing (reduce_kernel accumulates into them)
  hipMemsetAsync(d_ws, 0, (OFF_SUM + BATCH * NLAB * DIM) * sizeof(float), stream);

  dim3 grid1(G1X, BATCH);
  dim3 gridR((BATCH * NLAB * DIM + BATCH * NLAB + 255) / 256, 8);
  dim3 grid2(BPB2, BATCH);
  pass1_kernel<<<grid1, 256, 0, stream>>>(emb, lab, psum, pcnt);
  reduce_kernel<<<gridR, 256, 0, stream>>>(psum, pcnt, gsum, gcnt);
  pass2_kernel<<<grid2, 256, 0, stream>>>(emb, lab, gsum, gcnt, pullp);
  finish_kernel<<<1, 512, 0, stream>>>(gsum, gcnt, pullp, out);
}